// Round 9
// baseline (263.026 us; speedup 1.0000x reference)
//
#include <hip/hip_runtime.h>
#include <hip/hip_bf16.h>

// Problem constants
#define S_    2048
#define DIM_  1024
#define H_    16
#define DH_   64
#define BOT_  256
#define NIMG_ 4
#define LI_   512
#define K_    256
#define IH_   4
#define ID_   16
#define MAXREL_ 64
#define NBUCK_ 129
#define GH_   8
#define IDH2_ 128   // 2*IH*ID

typedef short bf16x8 __attribute__((ext_vector_type(8)));
typedef float f32x4  __attribute__((ext_vector_type(4)));

__device__ __forceinline__ unsigned short f2bf(float x) {   // RNE float->bf16
    unsigned u = __float_as_uint(x);
    return (unsigned short)((u + 0x7fffu + ((u >> 16) & 1u)) >> 16);
}
__device__ __forceinline__ float bf2f(unsigned short h) {
    return __uint_as_float(((unsigned)h) << 16);
}

// Split-region element offsets (ushort units). W1 = [Wqkv_d;Wq;Wk] contiguous.
#define OFF_W1_    2097152
#define OFF_WQ_    2359296
#define OFF_WK_    2490368
#define OFF_WQKVU_ 2621440
#define OFF_WPD_   3407872
#define OFF_WPU_   3670016
#define NSPLIT_    3932160
#define NTRIG_     65536      // S_*32 cos/sin table entries

// ---------------------------------------------------------------------------
// Fused hi/lo bf16 split of hidden + all 6 weight matrices + cos/sin tables.
// ---------------------------------------------------------------------------
__global__ __launch_bounds__(256) void split_all_kernel(
    const float* __restrict__ hid, const float* __restrict__ wqd,
    const float* __restrict__ wq,  const float* __restrict__ wk,
    const float* __restrict__ wqu, const float* __restrict__ wpd,
    const float* __restrict__ wpu, const float* __restrict__ rope,
    unsigned short* __restrict__ hi, unsigned short* __restrict__ lo,
    float* __restrict__ cost, float* __restrict__ sint)
{
    long e = ((long)blockIdx.x * 256 + threadIdx.x) * 4;
    if (e >= NSPLIT_ + NTRIG_) return;
    if (e >= NSPLIT_) {                      // trig-table segment
        long t = e - NSPLIT_;
        float4 r = *(const float4*)(rope + t);
        float4 c, s;
        c.x = cosf(r.x); s.x = sinf(r.x);
        c.y = cosf(r.y); s.y = sinf(r.y);
        c.z = cosf(r.z); s.z = sinf(r.z);
        c.w = cosf(r.w); s.w = sinf(r.w);
        *(float4*)&cost[t] = c;
        *(float4*)&sint[t] = s;
        return;
    }
    const float* src; long off;
    if (e < OFF_W1_)         { src = hid; off = 0; }
    else if (e < OFF_WQ_)    { src = wqd; off = OFF_W1_; }
    else if (e < OFF_WK_)    { src = wq;  off = OFF_WQ_; }
    else if (e < OFF_WQKVU_) { src = wk;  off = OFF_WK_; }
    else if (e < OFF_WPD_)   { src = wqu; off = OFF_WQKVU_; }
    else if (e < OFF_WPU_)   { src = wpd; off = OFF_WPD_; }
    else                     { src = wpu; off = OFF_WPU_; }
    float4 v = *(const float4*)(src + (e - off));
    ushort4 h, l;
    h.x = f2bf(v.x); l.x = f2bf(v.x - bf2f(h.x));
    h.y = f2bf(v.y); l.y = f2bf(v.y - bf2f(h.y));
    h.z = f2bf(v.z); l.z = f2bf(v.z - bf2f(h.z));
    h.w = f2bf(v.w); l.w = f2bf(v.w - bf2f(h.w));
    *(ushort4*)&hi[e] = h;
    *(ushort4*)&lo[e] = l;
}

// ---------------------------------------------------------------------------
// bf16x3 MFMA GEMM, 128x64 tile (large-N: p_u). fp32 out. (unchanged)
// ---------------------------------------------------------------------------
__global__ __launch_bounds__(256) void gemm_bf16x3(
    const unsigned short* __restrict__ Ah, const unsigned short* __restrict__ Al,
    const unsigned short* __restrict__ Bh, const unsigned short* __restrict__ Bl,
    const float* __restrict__ bias, const float* __restrict__ scale_ptr,
    float* __restrict__ Cf, int M, int N, int Kd)
{
    __shared__ unsigned short sAh[128 * 40], sAl[128 * 40];
    __shared__ unsigned short sBh[64 * 40],  sBl[64 * 40];
    int tid = threadIdx.x;
    int lane = tid & 63, wv = tid >> 6;
    int wr = wv >> 1, wc = wv & 1;
    int row0 = blockIdx.y * 128, col0 = blockIdx.x * 64;

    f32x4 acc[4][2];
#pragma unroll
    for (int i = 0; i < 4; i++)
#pragma unroll
        for (int j = 0; j < 2; j++) acc[i][j] = (f32x4){0.f, 0.f, 0.f, 0.f};

    int ar = tid >> 1, ac = (tid & 1) * 16;
    int br = tid >> 2, bc = (tid & 3) * 8;
    const unsigned short* gAh = Ah + (size_t)(row0 + ar) * Kd + ac;
    const unsigned short* gAl = Al + (size_t)(row0 + ar) * Kd + ac;
    const unsigned short* gBh = Bh + (size_t)(col0 + br) * Kd + bc;
    const unsigned short* gBl = Bl + (size_t)(col0 + br) * Kd + bc;
    int am = lane & 15, qk = (lane >> 4) * 8;

    for (int k0 = 0; k0 < Kd; k0 += 32) {
        __syncthreads();
        *(float4*)&sAh[ar * 40 + ac]     = *(const float4*)(gAh + k0);
        *(float4*)&sAh[ar * 40 + ac + 8] = *(const float4*)(gAh + k0 + 8);
        *(float4*)&sAl[ar * 40 + ac]     = *(const float4*)(gAl + k0);
        *(float4*)&sAl[ar * 40 + ac + 8] = *(const float4*)(gAl + k0 + 8);
        *(float4*)&sBh[br * 40 + bc]     = *(const float4*)(gBh + k0);
        *(float4*)&sBl[br * 40 + bc]     = *(const float4*)(gBl + k0);
        __syncthreads();

        bf16x8 ah[4], al[4], bh[2], bl[2];
#pragma unroll
        for (int rt = 0; rt < 4; rt++) {
            int r = wr * 64 + rt * 16 + am;
            ah[rt] = *(const bf16x8*)&sAh[r * 40 + qk];
            al[rt] = *(const bf16x8*)&sAl[r * 40 + qk];
        }
#pragma unroll
        for (int ct = 0; ct < 2; ct++) {
            int c = wc * 32 + ct * 16 + am;
            bh[ct] = *(const bf16x8*)&sBh[c * 40 + qk];
            bl[ct] = *(const bf16x8*)&sBl[c * 40 + qk];
        }
#pragma unroll
        for (int rt = 0; rt < 4; rt++)
#pragma unroll
            for (int ct = 0; ct < 2; ct++) {
                acc[rt][ct] = __builtin_amdgcn_mfma_f32_16x16x32_bf16(ah[rt], bh[ct], acc[rt][ct], 0, 0, 0);
                acc[rt][ct] = __builtin_amdgcn_mfma_f32_16x16x32_bf16(ah[rt], bl[ct], acc[rt][ct], 0, 0, 0);
                acc[rt][ct] = __builtin_amdgcn_mfma_f32_16x16x32_bf16(al[rt], bh[ct], acc[rt][ct], 0, 0, 0);
            }
    }

    float scl = scale_ptr ? *scale_ptr : 1.0f;
    int rq = (lane >> 4) * 4;
#pragma unroll
    for (int rt = 0; rt < 4; rt++)
#pragma unroll
        for (int ct = 0; ct < 2; ct++) {
            int col = col0 + wc * 32 + ct * 16 + am;
            float bz = bias ? bias[col] : 0.0f;
#pragma unroll
            for (int rg = 0; rg < 4; rg++) {
                int row = row0 + wr * 64 + rt * 16 + rq + rg;
                Cf[(size_t)row * N + col] = (acc[rt][ct][rg] + bz) * scl;
            }
        }
}

// ---------------------------------------------------------------------------
// bf16x3 MFMA GEMM, 64x64 tile, BK=64 (gemm1 N=512 split epilogue, p_d N=256).
// ---------------------------------------------------------------------------
__global__ __launch_bounds__(256) void gemm64_bf16x3(
    const unsigned short* __restrict__ Ah, const unsigned short* __restrict__ Al,
    const unsigned short* __restrict__ Bh, const unsigned short* __restrict__ Bl,
    const float* __restrict__ bias_lo, const float* __restrict__ bias_hi,
    float* __restrict__ Cf, unsigned short* __restrict__ Chi,
    unsigned short* __restrict__ Clo, int M, int N, int Kd, int split_col)
{
    __shared__ unsigned short sAh[64 * 72], sAl[64 * 72];
    __shared__ unsigned short sBh[64 * 72], sBl[64 * 72];
    int tid = threadIdx.x;
    int lane = tid & 63, wv = tid >> 6;
    int wr = wv >> 1, wc = wv & 1;          // wave 32x32
    int row0 = blockIdx.y * 64, col0 = blockIdx.x * 64;

    f32x4 acc[2][2];
#pragma unroll
    for (int i = 0; i < 2; i++)
#pragma unroll
        for (int j = 0; j < 2; j++) acc[i][j] = (f32x4){0.f, 0.f, 0.f, 0.f};

    int sr = tid >> 2, sc = (tid & 3) * 16;   // row, 16-elem chunk of 64
    const unsigned short* gAh = Ah + (size_t)(row0 + sr) * Kd + sc;
    const unsigned short* gAl = Al + (size_t)(row0 + sr) * Kd + sc;
    const unsigned short* gBh = Bh + (size_t)(col0 + sr) * Kd + sc;
    const unsigned short* gBl = Bl + (size_t)(col0 + sr) * Kd + sc;
    int am = lane & 15, qk = (lane >> 4) * 8;

    for (int k0 = 0; k0 < Kd; k0 += 64) {
        __syncthreads();
        *(float4*)&sAh[sr * 72 + sc]     = *(const float4*)(gAh + k0);
        *(float4*)&sAh[sr * 72 + sc + 8] = *(const float4*)(gAh + k0 + 8);
        *(float4*)&sAl[sr * 72 + sc]     = *(const float4*)(gAl + k0);
        *(float4*)&sAl[sr * 72 + sc + 8] = *(const float4*)(gAl + k0 + 8);
        *(float4*)&sBh[sr * 72 + sc]     = *(const float4*)(gBh + k0);
        *(float4*)&sBh[sr * 72 + sc + 8] = *(const float4*)(gBh + k0 + 8);
        *(float4*)&sBl[sr * 72 + sc]     = *(const float4*)(gBl + k0);
        *(float4*)&sBl[sr * 72 + sc + 8] = *(const float4*)(gBl + k0 + 8);
        __syncthreads();

#pragma unroll
        for (int ks = 0; ks < 2; ks++) {
            bf16x8 ah[2], al[2], bh[2], bl[2];
#pragma unroll
            for (int rt = 0; rt < 2; rt++) {
                int r = wr * 32 + rt * 16 + am;
                ah[rt] = *(const bf16x8*)&sAh[r * 72 + ks * 32 + qk];
                al[rt] = *(const bf16x8*)&sAl[r * 72 + ks * 32 + qk];
            }
#pragma unroll
            for (int ct = 0; ct < 2; ct++) {
                int c = wc * 32 + ct * 16 + am;
                bh[ct] = *(const bf16x8*)&sBh[c * 72 + ks * 32 + qk];
                bl[ct] = *(const bf16x8*)&sBl[c * 72 + ks * 32 + qk];
            }
#pragma unroll
            for (int rt = 0; rt < 2; rt++)
#pragma unroll
                for (int ct = 0; ct < 2; ct++) {
                    acc[rt][ct] = __builtin_amdgcn_mfma_f32_16x16x32_bf16(ah[rt], bh[ct], acc[rt][ct], 0, 0, 0);
                    acc[rt][ct] = __builtin_amdgcn_mfma_f32_16x16x32_bf16(ah[rt], bl[ct], acc[rt][ct], 0, 0, 0);
                    acc[rt][ct] = __builtin_amdgcn_mfma_f32_16x16x32_bf16(al[rt], bh[ct], acc[rt][ct], 0, 0, 0);
                }
        }
    }

    int rq = (lane >> 4) * 4;
#pragma unroll
    for (int rt = 0; rt < 2; rt++)
#pragma unroll
        for (int ct = 0; ct < 2; ct++) {
            int col = col0 + wc * 32 + ct * 16 + am;
#pragma unroll
            for (int rg = 0; rg < 4; rg++) {
                int row = row0 + wr * 32 + rt * 16 + rq + rg;
                float v = acc[rt][ct][rg];
                if (col < split_col) {
                    if (bias_lo) v += bias_lo[col];
                    size_t idx = (size_t)row * split_col + col;
                    unsigned short hh = f2bf(v);
                    Chi[idx] = hh;
                    Clo[idx] = f2bf(v - bf2f(hh));
                } else {
                    if (bias_hi) v += bias_hi[col - split_col];
                    Cf[(size_t)row * (N - split_col) + col - split_col] = v;
                }
            }
        }
}

// ---------------------------------------------------------------------------
// Fused dual-grid kernel (R9): blocks [0,512) run the score_topk body
// (R5/R8-exact); blocks [512,1280) run the gemm_qkv_rope body (R8-exact,
// with table-lookup cos/sin). The two are data-independent (both consume
// only gemm1's outputs) and overlap on the CUs: score is barrier/latency-
// bound at low occupancy, gemm is MFMA-heavy -- separate pipes co-schedule
// (m114). LDS is a 50688-byte union (score 50496 B, gemm 30720 B).
// ---------------------------------------------------------------------------
#define SCORE_BLOCKS_ 512

__device__ __forceinline__ void score_body(
    char* smem,
    const float* __restrict__ qIk,
    const int* __restrict__ coords, const float* __restrict__ rpe_table,
    const float* __restrict__ W1g, const float* __restrict__ b1g,
    const float* __restrict__ W2g, const float* __restrict__ b2g,
    unsigned* __restrict__ selmask)
{
    float    (*skI)[132]  = (float(*)[132])smem;                // 33792 B
    float    (*sqI2)[128] = (float(*)[128])(smem + 33792);      //  2048 B
    unsigned (*skeys)[512]= (unsigned(*)[512])(smem + 35840);   //  8192 B
    int      (*shist)[256]= (int(*)[256])(smem + 44032);        //  4096 B
    float*   srpe = (float*)(smem + 48128);                     //  2064 B
    float*   sW1  = (float*)(smem + 50192);                     //   128 B
    float*   sb1  = (float*)(smem + 50320);                     //    32 B
    float*   sW2  = (float*)(smem + 50352);                     //   128 B
    float*   sb2  = (float*)(smem + 50480);                     //    16 B

    int tid  = threadIdx.x;
    int lane = tid & 63;
    int wv   = tid >> 6;
    int row  = blockIdx.x * 4 + wv;
    int n    = (blockIdx.x * 4) >> 9;

    for (int i = tid; i < NBUCK_ * IH_; i += 256) srpe[i] = rpe_table[i];
    if (tid < 32) sW1[tid] = W1g[tid];
    else if (tid < 64) sW2[tid - 32] = W2g[tid - 32];
    else if (tid < 72) sb1[tid - 64] = b1g[tid - 64];
    else if (tid < 76) sb2[tid - 72] = b2g[tid - 72];
    for (int i = tid; i < 4 * IDH2_; i += 256)
        sqI2[i >> 7][i & 127] =
            qIk[(size_t)(blockIdx.x * 4 + (i >> 7)) * 256 + (i & 127)];
    int pq = coords[row * 2 + 1];

    for (int kt = 0; kt < 8; kt++) {
        __syncthreads();
        {
            int r  = tid >> 2;
            int d0 = (tid & 3) * 32;
            const float* src = qIk + (size_t)(n * LI_ + kt * 64 + r) * 256 + 128 + d0;
#pragma unroll
            for (int j = 0; j < 8; j++)
                *(float4*)&skI[r][d0 + j * 4] = *(const float4*)(src + j * 4);
        }
        __syncthreads();

        int kloc = lane;
        int kg   = kt * 64 + kloc;
        const float* sq = &sqI2[wv][0];
        float dh[8];
#pragma unroll
        for (int hh = 0; hh < 8; hh++) {
            float acc = 0.0f;
#pragma unroll
            for (int d = 0; d < 16; d += 4) {
                float4 kv = *(const float4*)&skI[kloc][hh * 16 + d];
                acc += sq[hh * 16 + d + 0] * kv.x + sq[hh * 16 + d + 1] * kv.y +
                       sq[hh * 16 + d + 2] * kv.z + sq[hh * 16 + d + 3] * kv.w;
            }
            dh[hh] = acc;
        }
        int pk = coords[(n * LI_ + kg) * 2 + 1];
        int rel = pq - pk;
        rel = rel < -MAXREL_ ? -MAXREL_ : (rel > MAXREL_ ? MAXREL_ : rel);
        const float* rp = srpe + (rel + MAXREL_) * IH_;
        float t1[GH_];
#pragma unroll
        for (int g = 0; g < GH_; g++) t1[g] = sb1[g];
#pragma unroll
        for (int j = 0; j < IH_; j++) {
            float gate = dh[IH_ + j] + rp[j];
#pragma unroll
            for (int g = 0; g < GH_; g++) t1[g] += gate * sW1[g * IH_ + j];
        }
#pragma unroll
        for (int g = 0; g < GH_; g++) t1[g] = fmaxf(t1[g], 0.0f);
        float score = 0.0f;
#pragma unroll
        for (int j = 0; j < IH_; j++) {
            float t2 = sb2[j];
#pragma unroll
            for (int g = 0; g < GH_; g++) t2 += t1[g] * sW2[j * GH_ + g];
            float sg = 1.0f / (1.0f + expf(-t2));
            float rs = fmaxf(dh[j] + rp[j], 0.0f);
            score += rs * sg;
        }
        unsigned bits = __float_as_uint(score);
        skeys[wv][kg] = (bits & 0x80000000u) ? ~bits : (bits | 0x80000000u);
    }
    // no barrier: skeys[wv]/shist[wv] per-wave; same-wave DS ops in-order

    unsigned pref = 0u;
    int kcur = K_;
    const unsigned himask[4] = {0u, 0xFF000000u, 0xFFFF0000u, 0xFFFFFF00u};
#pragma unroll
    for (int pass = 0; pass < 4; pass++) {
        int shift = 24 - pass * 8;
        unsigned hm = himask[pass];
        *(int4*)&shist[wv][4 * lane] = make_int4(0, 0, 0, 0);
#pragma unroll
        for (int c = 0; c < 8; c++) {
            unsigned key = skeys[wv][c * 64 + lane];
            if ((key & hm) == pref) atomicAdd(&shist[wv][(key >> shift) & 255], 1);
        }
        int4 b4 = *(const int4*)&shist[wv][4 * lane];
        int b[4] = {b4.x, b4.y, b4.z, b4.w};
        int t = b[0] + b[1] + b[2] + b[3];
        int Ssum = t;
#pragma unroll
        for (int off = 1; off < 64; off <<= 1) {
            int u = __shfl_down(Ssum, off, 64);
            if (lane + off < 64) Ssum += u;
        }
        int E = Ssum - t;
        int cs[5];
        cs[4] = E;
        cs[3] = b[3] + E;
        cs[2] = b[2] + cs[3];
        cs[1] = b[1] + cs[2];
        cs[0] = b[0] + cs[1];
        bool found = false;
        unsigned cpref = 0u; int ck = 0;
#pragma unroll
        for (int j = 0; j < 4; j++) {
            if (!found && cs[j] >= kcur && cs[j + 1] < kcur) {
                found = true;
                cpref = pref | ((unsigned)(4 * lane + j) << shift);
                ck = kcur - cs[j + 1];
            }
        }
        unsigned long long bm = __ballot(found);
        int src = __ffsll((long long)bm) - 1;
        pref = (unsigned)__shfl((int)cpref, src, 64);
        kcur = __shfl(ck, src, 64);
    }
    unsigned Tu = pref;

    unsigned long long bg[8], be[8];
#pragma unroll
    for (int c = 0; c < 8; c++) {
        unsigned key = skeys[wv][c * 64 + lane];
        bg[c] = __ballot(key > Tu);
        be[c] = __ballot(key == Tu);
    }
    if (lane < 16) {
        int total_gt = 0;
#pragma unroll
        for (int c = 0; c < 8; c++) total_gt += __popcll(bg[c]);
        int base = 0;
#pragma unroll
        for (int c = 0; c < 8; c++) {
            if (2 * c < lane)     base += __popc((unsigned)be[c]);
            if (2 * c + 1 < lane) base += __popc((unsigned)(be[c] >> 32));
        }
        unsigned gw = (unsigned)(bg[lane >> 1] >> (32 * (lane & 1)));
        unsigned ew = (unsigned)(be[lane >> 1] >> (32 * (lane & 1)));
        int ne = K_ - total_gt - base;
        int pc = __popc(ew);
        int m = ne < 0 ? 0 : (ne > pc ? pc : ne);
        while (pc > m) { ew ^= (1u << (31 - __clz(ew))); pc--; }
        selmask[(size_t)row * 16 + lane] = gw | ew;
    }
}

__device__ __forceinline__ void gemm_qkv_body(
    char* smem, int gb,
    const unsigned short* __restrict__ Ah, const unsigned short* __restrict__ Al,
    const unsigned short* __restrict__ Bh, const unsigned short* __restrict__ Bl,
    const float* __restrict__ bias, const float* __restrict__ cost,
    const float* __restrict__ sint,
    unsigned short* __restrict__ qkvh, unsigned short* __restrict__ qkvl)
{
    unsigned short* sAh = (unsigned short*)smem;      // 128*40*2 = 10240 B
    unsigned short* sAl = sAh + 128 * 40;             // 10240 B
    unsigned short* sBh = sAl + 128 * 40;             //  5120 B
    unsigned short* sBl = sBh + 64 * 40;              //  5120 B -> 30720 B

    int bx = gb % 48, by = gb / 48;
    int tid = threadIdx.x;
    int lane = tid & 63, wv = tid >> 6;
    int wr = wv >> 1, wc = wv & 1;
    int row0 = by * 128, col0 = bx * 64;
    const int Kd = BOT_;

    f32x4 acc[4][2];
#pragma unroll
    for (int i = 0; i < 4; i++)
#pragma unroll
        for (int j = 0; j < 2; j++) acc[i][j] = (f32x4){0.f, 0.f, 0.f, 0.f};

    int ar = tid >> 1, ac = (tid & 1) * 16;
    int br = tid >> 2, bc = (tid & 3) * 8;
    const unsigned short* gAh = Ah + (size_t)(row0 + ar) * Kd + ac;
    const unsigned short* gAl = Al + (size_t)(row0 + ar) * Kd + ac;
    const unsigned short* gBh = Bh + (size_t)(col0 + br) * Kd + bc;
    const unsigned short* gBl = Bl + (size_t)(col0 + br) * Kd + bc;
    int am = lane & 15, qk = (lane >> 4) * 8;

    for (int k0 = 0; k0 < Kd; k0 += 32) {
        __syncthreads();
        *(float4*)&sAh[ar * 40 + ac]     = *(const float4*)(gAh + k0);
        *(float4*)&sAh[ar * 40 + ac + 8] = *(const float4*)(gAh + k0 + 8);
        *(float4*)&sAl[ar * 40 + ac]     = *(const float4*)(gAl + k0);
        *(float4*)&sAl[ar * 40 + ac + 8] = *(const float4*)(gAl + k0 + 8);
        *(float4*)&sBh[br * 40 + bc]     = *(const float4*)(gBh + k0);
        *(float4*)&sBl[br * 40 + bc]     = *(const float4*)(gBl + k0);
        __syncthreads();

        bf16x8 ah[4], al[4], bh[2], bl[2];
#pragma unroll
        for (int rt = 0; rt < 4; rt++) {
            int r = wr * 64 + rt * 16 + am;
            ah[rt] = *(const bf16x8*)&sAh[r * 40 + qk];
            al[rt] = *(const bf16x8*)&sAl[r * 40 + qk];
        }
#pragma unroll
        for (int ct = 0; ct < 2; ct++) {
            int c = ct * 32 + wc * 16 + am;      // remapped: rope pair in-reg
            bh[ct] = *(const bf16x8*)&sBh[c * 40 + qk];
            bl[ct] = *(const bf16x8*)&sBl[c * 40 + qk];
        }
#pragma unroll
        for (int rt = 0; rt < 4; rt++)
#pragma unroll
            for (int ct = 0; ct < 2; ct++) {
                acc[rt][ct] = __builtin_amdgcn_mfma_f32_16x16x32_bf16(ah[rt], bh[ct], acc[rt][ct], 0, 0, 0);
                acc[rt][ct] = __builtin_amdgcn_mfma_f32_16x16x32_bf16(ah[rt], bl[ct], acc[rt][ct], 0, 0, 0);
                acc[rt][ct] = __builtin_amdgcn_mfma_f32_16x16x32_bf16(al[rt], bh[ct], acc[rt][ct], 0, 0, 0);
            }
    }

    int sec  = bx >> 4;                // 0=q, 1=k, 2=v
    int hd   = bx & 15;
    int d_lo = wc * 16 + am;           // 0..31
    float b1 = bias[col0 + d_lo];
    float b2 = bias[col0 + 32 + d_lo];
    int rq = (lane >> 4) * 4;
#pragma unroll
    for (int rt = 0; rt < 4; rt++)
#pragma unroll
        for (int rg = 0; rg < 4; rg++) {
            int row = row0 + wr * 64 + rt * 16 + rq + rg;
            float x1 = acc[rt][0][rg] + b1;
            float x2 = acc[rt][1][rg] + b2;
            float o1, o2;
            if (sec < 2) {
                float cs = cost[row * 32 + d_lo];
                float sn = sint[row * 32 + d_lo];
                o1 = x1 * cs - x2 * sn;
                o2 = x2 * cs + x1 * sn;
                if (sec == 0) { o1 *= 0.125f; o2 *= 0.125f; }
            } else {
                o1 = x1; o2 = x2;
            }
            size_t base = (size_t)row * 3072 + sec * 1024 + hd * 64 + d_lo;
            unsigned short h1 = f2bf(o1);
            qkvh[base] = h1;       qkvl[base] = f2bf(o1 - bf2f(h1));
            unsigned short h2 = f2bf(o2);
            qkvh[base + 32] = h2;  qkvl[base + 32] = f2bf(o2 - bf2f(h2));
        }
}

__global__ __launch_bounds__(256) void score_qkv_fused(
    const float* __restrict__ qIk,
    const int* __restrict__ coords, const float* __restrict__ rpe_table,
    const float* __restrict__ W1g, const float* __restrict__ b1g,
    const float* __restrict__ W2g, const float* __restrict__ b2g,
    unsigned* __restrict__ selmask,
    const unsigned short* __restrict__ Ah, const unsigned short* __restrict__ Al,
    const unsigned short* __restrict__ Bh, const unsigned short* __restrict__ Bl,
    const float* __restrict__ bias, const float* __restrict__ cost,
    const float* __restrict__ sint,
    unsigned short* __restrict__ qkvh, unsigned short* __restrict__ qkvl)
{
    __shared__ __align__(16) char smem[50688];
    if (blockIdx.x < SCORE_BLOCKS_) {
        score_body(smem, qIk, coords, rpe_table, W1g, b1g, W2g, b2g, selmask);
    } else {
        gemm_qkv_body(smem, blockIdx.x - SCORE_BLOCKS_,
                      Ah, Al, Bh, Bl, bias, cost, sint, qkvh, qkvl);
    }
}

// ---------------------------------------------------------------------------
// Dense-masked attention v7 (R7-exact): T14 async-STAGE prefetch, Q frags
// hoisted, setprio around MFMA clusters, separate P buffer, 2 barriers/kt.
// ---------------------------------------------------------------------------
__global__ __launch_bounds__(256) void attn_kernel(
    const unsigned short* __restrict__ qkvh, const unsigned short* __restrict__ qkvl,
    const unsigned* __restrict__ selmask,
    unsigned short* __restrict__ outh, unsigned short* __restrict__ outl)
{
    __shared__ unsigned short Qh[64 * 72],  Ql[64 * 72];   // [q][d]
    __shared__ unsigned short Kh[64 * 72],  Kl[64 * 72];   // [key][d]
    __shared__ unsigned short VTh[64 * 72], VTl[64 * 72];  // V^T [d][key]
    __shared__ unsigned short Ph[64 * 72],  Pl[64 * 72];   // P [q][key]
    __shared__ unsigned Ms[64][16];

    int b  = blockIdx.x;
    int qt = b >> 6;                 // XCD swizzle: qt in high bits
    int nh = b & 63;
    int h  = nh & 15;
    int n  = nh >> 4;
    int tid = threadIdx.x;
    int lane = tid & 63, w = tid >> 6;
    int lane15 = lane & 15, quad = lane >> 4;
    int q0 = n * LI_ + qt * 64;

    for (int i = tid; i < 64 * 16; i += 256)
        Ms[i >> 4][i & 15] = selmask[(size_t)(q0 + (i >> 4)) * 16 + (i & 15)];

    // stage Q once (already rope'd, scaled, split)
    {
        int r = tid >> 2, c0 = (tid & 3) * 16;
        size_t off = (size_t)(q0 + r) * 3072 + h * 64 + c0;
        *(uint4*)&Qh[r * 72 + c0]     = *(const uint4*)(qkvh + off);
        *(uint4*)&Qh[r * 72 + c0 + 8] = *(const uint4*)(qkvh + off + 8);
        *(uint4*)&Ql[r * 72 + c0]     = *(const uint4*)(qkvl + off);
        *(uint4*)&Ql[r * 72 + c0 + 8] = *(const uint4*)(qkvl + off + 8);
    }
    __syncthreads();   // Q staged -> hoist fragments to registers once
    bf16x8 qfh[2], qfl[2];
#pragma unroll
    for (int ks = 0; ks < 2; ks++) {
        qfh[ks] = *(const bf16x8*)&Qh[(16 * w + lane15) * 72 + ks * 32 + quad * 8];
        qfl[ks] = *(const bf16x8*)&Ql[(16 * w + lane15) * 72 + ks * 32 + quad * 8];
    }

    // prefetch addressing (constant per thread)
    int kr = tid >> 2, kc0 = (tid & 3) * 16;          // K stage coords
    int vd = lane, vk0 = w * 16;                      // V stage coords
    const size_t kbase = (size_t)n * LI_ * 3072 + 1024 + h * 64;
    const size_t vbase = (size_t)n * LI_ * 3072 + 2048 + h * 64;

    uint4 pkh0, pkh1, pkl0, pkl1;                     // K prefetch regs
    unsigned short pvh[16], pvl[16];                  // V prefetch regs

#define LOADT(KT)                                                              \
    {                                                                          \
        size_t offK = kbase + (size_t)((KT) * 64 + kr) * 3072 + kc0;           \
        pkh0 = *(const uint4*)(qkvh + offK);                                   \
        pkh1 = *(const uint4*)(qkvh + offK + 8);                               \
        pkl0 = *(const uint4*)(qkvl + offK);                                   \
        pkl1 = *(const uint4*)(qkvl + offK + 8);                               \
        size_t offV = vbase + (size_t)((KT) * 64 + vk0) * 3072 + vd;           \
        _Pragma("unroll")                                                      \
        for (int j = 0; j < 16; j++) {                                         \
            pvh[j] = qkvh[offV + (size_t)j * 3072];                            \
            pvl[j] = qkvl[offV + (size_t)j * 3072];                            \
        }                                                                      \
    }

    LOADT(0);

    f32x4 o_acc[4];
#pragma unroll
    for (int i = 0; i < 4; i++) o_acc[i] = (f32x4){0.f, 0.f, 0.f, 0.f};
    float rsum[4] = {};

    for (int kt = 0; kt < 8; kt++) {
        __syncthreads();   // prev iter's Kh (QK) and VTh (PV) reads done
        // reg -> LDS writes only (loads were issued last iteration)
        *(uint4*)&Kh[kr * 72 + kc0]      = pkh0;
        *(uint4*)&Kh[kr * 72 + kc0 + 8]  = pkh1;
        *(uint4*)&Kl[kr * 72 + kc0]      = pkl0;
        *(uint4*)&Kl[kr * 72 + kc0 + 8]  = pkl1;
        *(uint4*)&VTh[vd * 72 + vk0]     = *(uint4*)&pvh[0];
        *(uint4*)&VTh[vd * 72 + vk0 + 8] = *(uint4*)&pvh[8];
        *(uint4*)&VTl[vd * 72 + vk0]     = *(uint4*)&pvl[0];
        *(uint4*)&VTl[vd * 72 + vk0 + 8] = *(uint4*)&pvl[8];
        __syncthreads();   // stage visible to all waves

        // issue next tile's loads; latency hides under QK/softmax/PV
        if (kt < 7) LOADT(kt + 1);

        // QK: wave w computes q-tile w vs all 4 key-tiles, bf16x3
        f32x4 s_acc[4];
#pragma unroll
        for (int nt = 0; nt < 4; nt++) s_acc[nt] = (f32x4){0.f, 0.f, 0.f, 0.f};
        __builtin_amdgcn_s_setprio(1);
#pragma unroll
        for (int nt = 0; nt < 4; nt++) {
#pragma unroll
            for (int ks = 0; ks < 2; ks++) {
                bf16x8 kfh = *(const bf16x8*)&Kh[(16 * nt + lane15) * 72 + ks * 32 + quad * 8];
                bf16x8 kfl = *(const bf16x8*)&Kl[(16 * nt + lane15) * 72 + ks * 32 + quad * 8];
                s_acc[nt] = __builtin_amdgcn_mfma_f32_16x16x32_bf16(qfh[ks], kfh, s_acc[nt], 0, 0, 0);
                s_acc[nt] = __builtin_amdgcn_mfma_f32_16x16x32_bf16(qfh[ks], kfl, s_acc[nt], 0, 0, 0);
                s_acc[nt] = __builtin_amdgcn_mfma_f32_16x16x32_bf16(qfl[ks], kfh, s_acc[nt], 0, 0, 0);
            }
        }
        __builtin_amdgcn_s_setprio(0);

        // softmax + P split; writes only this wave's P rows -> no barrier
#pragma unroll
        for (int nt = 0; nt < 4; nt++) {
            int kb = kt * 64 + nt * 16 + lane15;
            int wi = kb >> 5, bit = kb & 31;
#pragma unroll
            for (int reg = 0; reg < 4; reg++) {
                int qloc = 16 * w + quad * 4 + reg;
                unsigned mw = Ms[qloc][wi];
                float p = ((mw >> bit) & 1u) ? __expf(s_acc[nt][reg]) : 0.0f;
                rsum[reg] += p;
                unsigned short ph = f2bf(p);
                Ph[qloc * 72 + nt * 16 + lane15] = ph;
                Pl[qloc * 72 + nt * 16 + lane15] = f2bf(p - bf2f(ph));
            }
        }

        // PV: A = P [q][key] (own rows), B = V^T [d][key], bf16x3
        {
            bf16x8 pfh[2], pfl[2];
#pragma unroll
            for (int ks = 0; ks < 2; ks++) {
                pfh[ks] = *(const bf16x8*)&Ph[(16 * w + lane15) * 72 + ks * 32 + quad * 8];
                pfl[ks] = *(const bf16x8*)&Pl[(16 * w + lane15) * 72 + ks * 32 + quad * 8];
            }
            __builtin_amdgcn_s_setprio(1);
#pragma unroll
            for (int dt = 0; dt < 4; dt++) {
#pragma unroll
                for (int ks = 0; ks < 2; ks++) {
                    bf16x8 vfh = *(const bf16x8*)&VTh[(16 * dt + lane15) * 72 + ks * 32 + quad * 8];
                    bf16x8 vfl = *(const bf16x8*)&VTl[(16 * dt + lane15) * 72 + ks * 32 + quad * 8];
                    o_acc[dt] = __builtin_amdgcn_mfma_f32_16x16x32_bf16(pfh[ks], vfh, o_acc[dt], 0, 0, 0);
                    o_acc[dt] = __builtin_amdgcn_mfma_f32_16x16x32_bf16(pfh[ks], vfl, o_acc[dt], 0, 0, 0);
                    o_acc[dt] = __builtin_amdgcn_mfma_f32_16x16x32_bf16(pfl[ks], vfh, o_acc[dt], 0, 0, 0);
                }
            }
            __builtin_amdgcn_s_setprio(0);
        }
    }
#undef LOADT

    // row sums: reduce over the 16 lanes (lane15) sharing each q row
#pragma unroll
    for (int reg = 0; reg < 4; reg++) {
        rsum[reg] += __shfl_xor(rsum[reg], 1, 64);
        rsum[reg] += __shfl_xor(rsum[reg], 2, 64);
        rsum[reg] += __shfl_xor(rsum[reg], 4, 64);
        rsum[reg] += __shfl_xor(rsum[reg], 8, 64);
    }

    // epilogue: normalize, split hi/lo, store
#pragma unroll
    for (int dt = 0; dt < 4; dt++) {
#pragma unroll
        for (int reg = 0; reg < 4; reg++) {
            float v = o_acc[dt][reg] / rsum[reg];
            size_t ob = (size_t)(q0 + 16 * w + quad * 4 + reg) * 1024 + h * 64 + 16 * dt + lane15;
            unsigned short hh = f2bf(v);
            outh[ob] = hh;
            outl[ob] = f2bf(v - bf2f(hh));
        }
    }
}

// ---------------------------------------------------------------------------
extern "C" void kernel_launch(void* const* d_in, const int* in_sizes, int n_in,
                              void* d_out, int out_size, void* d_ws, size_t ws_size,
                              hipStream_t stream)
{
    const float* hidden  = (const float*)d_in[0];
    const int*   coords  = (const int*)d_in[1];
    const float* rope    = (const float*)d_in[3];
    const float* Wq_idx  = (const float*)d_in[4];
    const float* Wk_idx  = (const float*)d_in[5];
    const float* W1g     = (const float*)d_in[6];
    const float* b1g     = (const float*)d_in[7];
    const float* W2g     = (const float*)d_in[8];
    const float* b2g     = (const float*)d_in[9];
    const float* rpe     = (const float*)d_in[10];
    const float* Wqkv_d  = (const float*)d_in[11];
    const float* bqkv_d  = (const float*)d_in[12];
    const float* Wqkv_u  = (const float*)d_in[13];
    const float* bqkv_u  = (const float*)d_in[14];
    const float* Wp_d    = (const float*)d_in[15];
    const float* bp_d    = (const float*)d_in[16];
    const float* Wp_u    = (const float*)d_in[17];
    const float* bp_u    = (const float*)d_in[18];
    const float* scaler  = (const float*)d_in[19];
    float* out = (float*)d_out;

    unsigned short* sp_hi  = (unsigned short*)d_ws;
    unsigned short* sp_lo  = sp_hi + NSPLIT_;
    unsigned short* mid_hi = sp_lo + NSPLIT_;
    unsigned short* mid_lo = mid_hi + (size_t)S_ * BOT_;
    float* qkv = (float*)(mid_lo + (size_t)S_ * BOT_);   // slot kept (unused)
    float* qIk = qkv + (size_t)S_ * 3 * DIM_;
    unsigned* selmask = (unsigned*)(qIk + (size_t)S_ * 256);
    unsigned short* qkvh = (unsigned short*)(selmask + (size_t)S_ * 16);
    unsigned short* qkvl = qkvh + (size_t)S_ * 3 * DIM_;
    float* cost = (float*)(qkvl + (size_t)S_ * 3 * DIM_);
    float* sint = cost + NTRIG_;

    // 0) split hidden + all weights into hi/lo bf16, precompute cos/sin
    split_all_kernel<<<((NSPLIT_ + NTRIG_) / 4 + 255) / 256, 256, 0, stream>>>(
        hidden, Wqkv_d, Wq_idx, Wk_idx, Wqkv_u, Wp_d, Wp_u, rope,
        sp_hi, sp_lo, cost, sint);

    // 1) fused gemm1: hidden @ [Wqkv_d;Wq;Wk]^T -> mid(hi/lo) + qIk(fp32)
    gemm64_bf16x3<<<dim3(512 / 64, S_ / 64), 256, 0, stream>>>(
        sp_hi, sp_lo, sp_hi + OFF_W1_, sp_lo + OFF_W1_,
        bqkv_d, nullptr, qIk, mid_hi, mid_lo, S_, 512, DIM_, 256);

    // 2) FUSED: score_topk (blocks 0..511) || gemm_qkv_rope (blocks 512..1279)
    //    -- independent work overlapped on the CUs, one dispatch
    score_qkv_fused<<<SCORE_BLOCKS_ + 768, 256, 0, stream>>>(
        qIk, coords, rpe, W1g, b1g, W2g, b2g, selmask,
        mid_hi, mid_lo, sp_hi + OFF_WQKVU_, sp_lo + OFF_WQKVU_,
        bqkv_u, cost, sint, qkvh, qkvl);

    // 3) MFMA attention (T14 prefetch; emits attout hi/lo into split slots)
    attn_kernel<<<NIMG_ * H_ * 8, 256, 0, stream>>>(qkvh, qkvl, selmask, sp_hi, sp_lo);

    // 4) mid2 = attout @ Wp_d^T + b (hi/lo)
    gemm64_bf16x3<<<dim3(BOT_ / 64, S_ / 64), 256, 0, stream>>>(
        sp_hi, sp_lo, sp_hi + OFF_WPD_, sp_lo + OFF_WPD_,
        bp_d, nullptr, nullptr, mid_hi, mid_lo, S_, BOT_, DIM_, BOT_);

    // 5) out = mid2 @ Wp_u^T + b, *scaler (fp32)
    gemm_bf16x3<<<dim3(DIM_ / 64, S_ / 128), 256, 0, stream>>>(
        mid_hi, mid_lo, sp_hi + OFF_WPU_, sp_lo + OFF_WPU_,
        bp_u, scaler, out, S_, DIM_, BOT_);
}

// Round 10
// 246.193 us; speedup vs baseline: 1.0684x; 1.0684x over previous
//
#include <hip/hip_runtime.h>
#include <hip/hip_bf16.h>

// Problem constants
#define S_    2048
#define DIM_  1024
#define H_    16
#define DH_   64
#define BOT_  256
#define NIMG_ 4
#define LI_   512
#define K_    256
#define IH_   4
#define ID_   16
#define MAXREL_ 64
#define NBUCK_ 129
#define GH_   8
#define IDH2_ 128   // 2*IH*ID

typedef short bf16x8 __attribute__((ext_vector_type(8)));
typedef float f32x4  __attribute__((ext_vector_type(4)));

__device__ __forceinline__ unsigned short f2bf(float x) {   // RNE float->bf16
    unsigned u = __float_as_uint(x);
    return (unsigned short)((u + 0x7fffu + ((u >> 16) & 1u)) >> 16);
}
__device__ __forceinline__ float bf2f(unsigned short h) {
    return __uint_as_float(((unsigned)h) << 16);
}

// Split-region element offsets (ushort units). W1 = [Wqkv_d;Wq;Wk] contiguous.
#define OFF_W1_    2097152
#define OFF_WQ_    2359296
#define OFF_WK_    2490368
#define OFF_WQKVU_ 2621440
#define OFF_WPD_   3407872
#define OFF_WPU_   3670016
#define NSPLIT_    3932160
#define NTRIG_     65536      // S_*32 cos/sin table entries

// ---------------------------------------------------------------------------
// Fused hi/lo bf16 split of hidden + all 6 weight matrices + cos/sin tables.
// ---------------------------------------------------------------------------
__global__ __launch_bounds__(256) void split_all_kernel(
    const float* __restrict__ hid, const float* __restrict__ wqd,
    const float* __restrict__ wq,  const float* __restrict__ wk,
    const float* __restrict__ wqu, const float* __restrict__ wpd,
    const float* __restrict__ wpu, const float* __restrict__ rope,
    unsigned short* __restrict__ hi, unsigned short* __restrict__ lo,
    float* __restrict__ cost, float* __restrict__ sint)
{
    long e = ((long)blockIdx.x * 256 + threadIdx.x) * 4;
    if (e >= NSPLIT_ + NTRIG_) return;
    if (e >= NSPLIT_) {                      // trig-table segment
        long t = e - NSPLIT_;
        float4 r = *(const float4*)(rope + t);
        float4 c, s;
        c.x = cosf(r.x); s.x = sinf(r.x);
        c.y = cosf(r.y); s.y = sinf(r.y);
        c.z = cosf(r.z); s.z = sinf(r.z);
        c.w = cosf(r.w); s.w = sinf(r.w);
        *(float4*)&cost[t] = c;
        *(float4*)&sint[t] = s;
        return;
    }
    const float* src; long off;
    if (e < OFF_W1_)         { src = hid; off = 0; }
    else if (e < OFF_WQ_)    { src = wqd; off = OFF_W1_; }
    else if (e < OFF_WK_)    { src = wq;  off = OFF_WQ_; }
    else if (e < OFF_WQKVU_) { src = wk;  off = OFF_WK_; }
    else if (e < OFF_WPD_)   { src = wqu; off = OFF_WQKVU_; }
    else if (e < OFF_WPU_)   { src = wpd; off = OFF_WPD_; }
    else                     { src = wpu; off = OFF_WPU_; }
    float4 v = *(const float4*)(src + (e - off));
    ushort4 h, l;
    h.x = f2bf(v.x); l.x = f2bf(v.x - bf2f(h.x));
    h.y = f2bf(v.y); l.y = f2bf(v.y - bf2f(h.y));
    h.z = f2bf(v.z); l.z = f2bf(v.z - bf2f(h.z));
    h.w = f2bf(v.w); l.w = f2bf(v.w - bf2f(h.w));
    *(ushort4*)&hi[e] = h;
    *(ushort4*)&lo[e] = l;
}

// ---------------------------------------------------------------------------
// bf16x3 MFMA GEMM, 128x64 tile (large-N: p_u). fp32 out. (unchanged)
// ---------------------------------------------------------------------------
__global__ __launch_bounds__(256) void gemm_bf16x3(
    const unsigned short* __restrict__ Ah, const unsigned short* __restrict__ Al,
    const unsigned short* __restrict__ Bh, const unsigned short* __restrict__ Bl,
    const float* __restrict__ bias, const float* __restrict__ scale_ptr,
    float* __restrict__ Cf, int M, int N, int Kd)
{
    __shared__ unsigned short sAh[128 * 40], sAl[128 * 40];
    __shared__ unsigned short sBh[64 * 40],  sBl[64 * 40];
    int tid = threadIdx.x;
    int lane = tid & 63, wv = tid >> 6;
    int wr = wv >> 1, wc = wv & 1;
    int row0 = blockIdx.y * 128, col0 = blockIdx.x * 64;

    f32x4 acc[4][2];
#pragma unroll
    for (int i = 0; i < 4; i++)
#pragma unroll
        for (int j = 0; j < 2; j++) acc[i][j] = (f32x4){0.f, 0.f, 0.f, 0.f};

    int ar = tid >> 1, ac = (tid & 1) * 16;
    int br = tid >> 2, bc = (tid & 3) * 8;
    const unsigned short* gAh = Ah + (size_t)(row0 + ar) * Kd + ac;
    const unsigned short* gAl = Al + (size_t)(row0 + ar) * Kd + ac;
    const unsigned short* gBh = Bh + (size_t)(col0 + br) * Kd + bc;
    const unsigned short* gBl = Bl + (size_t)(col0 + br) * Kd + bc;
    int am = lane & 15, qk = (lane >> 4) * 8;

    for (int k0 = 0; k0 < Kd; k0 += 32) {
        __syncthreads();
        *(float4*)&sAh[ar * 40 + ac]     = *(const float4*)(gAh + k0);
        *(float4*)&sAh[ar * 40 + ac + 8] = *(const float4*)(gAh + k0 + 8);
        *(float4*)&sAl[ar * 40 + ac]     = *(const float4*)(gAl + k0);
        *(float4*)&sAl[ar * 40 + ac + 8] = *(const float4*)(gAl + k0 + 8);
        *(float4*)&sBh[br * 40 + bc]     = *(const float4*)(gBh + k0);
        *(float4*)&sBl[br * 40 + bc]     = *(const float4*)(gBl + k0);
        __syncthreads();

        bf16x8 ah[4], al[4], bh[2], bl[2];
#pragma unroll
        for (int rt = 0; rt < 4; rt++) {
            int r = wr * 64 + rt * 16 + am;
            ah[rt] = *(const bf16x8*)&sAh[r * 40 + qk];
            al[rt] = *(const bf16x8*)&sAl[r * 40 + qk];
        }
#pragma unroll
        for (int ct = 0; ct < 2; ct++) {
            int c = wc * 32 + ct * 16 + am;
            bh[ct] = *(const bf16x8*)&sBh[c * 40 + qk];
            bl[ct] = *(const bf16x8*)&sBl[c * 40 + qk];
        }
#pragma unroll
        for (int rt = 0; rt < 4; rt++)
#pragma unroll
            for (int ct = 0; ct < 2; ct++) {
                acc[rt][ct] = __builtin_amdgcn_mfma_f32_16x16x32_bf16(ah[rt], bh[ct], acc[rt][ct], 0, 0, 0);
                acc[rt][ct] = __builtin_amdgcn_mfma_f32_16x16x32_bf16(ah[rt], bl[ct], acc[rt][ct], 0, 0, 0);
                acc[rt][ct] = __builtin_amdgcn_mfma_f32_16x16x32_bf16(al[rt], bh[ct], acc[rt][ct], 0, 0, 0);
            }
    }

    float scl = scale_ptr ? *scale_ptr : 1.0f;
    int rq = (lane >> 4) * 4;
#pragma unroll
    for (int rt = 0; rt < 4; rt++)
#pragma unroll
        for (int ct = 0; ct < 2; ct++) {
            int col = col0 + wc * 32 + ct * 16 + am;
            float bz = bias ? bias[col] : 0.0f;
#pragma unroll
            for (int rg = 0; rg < 4; rg++) {
                int row = row0 + wr * 64 + rt * 16 + rq + rg;
                Cf[(size_t)row * N + col] = (acc[rt][ct][rg] + bz) * scl;
            }
        }
}

// ---------------------------------------------------------------------------
// gemm_qkv_rope (R10): R8's fused gemm2+rope kernel, but epilogue trig comes
// from precomputed cos/sin TABLES (512 KB, L2-resident) instead of on-device
// cosf/sinf -- removes ~262K transcendental pairs from the critical path
// (Appendix B: trig-heavy epilogues turn compute-bound). Values identical.
// ---------------------------------------------------------------------------
__global__ __launch_bounds__(256) void gemm_qkv_rope(
    const unsigned short* __restrict__ Ah, const unsigned short* __restrict__ Al,
    const unsigned short* __restrict__ Bh, const unsigned short* __restrict__ Bl,
    const float* __restrict__ bias, const float* __restrict__ cost,
    const float* __restrict__ sint,
    unsigned short* __restrict__ qkvh, unsigned short* __restrict__ qkvl)
{
    __shared__ unsigned short sAh[128 * 40], sAl[128 * 40];
    __shared__ unsigned short sBh[64 * 40],  sBl[64 * 40];
    int tid = threadIdx.x;
    int lane = tid & 63, wv = tid >> 6;
    int wr = wv >> 1, wc = wv & 1;
    int row0 = blockIdx.y * 128, col0 = blockIdx.x * 64;
    const int Kd = BOT_;

    f32x4 acc[4][2];
#pragma unroll
    for (int i = 0; i < 4; i++)
#pragma unroll
        for (int j = 0; j < 2; j++) acc[i][j] = (f32x4){0.f, 0.f, 0.f, 0.f};

    int ar = tid >> 1, ac = (tid & 1) * 16;
    int br = tid >> 2, bc = (tid & 3) * 8;
    const unsigned short* gAh = Ah + (size_t)(row0 + ar) * Kd + ac;
    const unsigned short* gAl = Al + (size_t)(row0 + ar) * Kd + ac;
    const unsigned short* gBh = Bh + (size_t)(col0 + br) * Kd + bc;
    const unsigned short* gBl = Bl + (size_t)(col0 + br) * Kd + bc;
    int am = lane & 15, qk = (lane >> 4) * 8;

    for (int k0 = 0; k0 < Kd; k0 += 32) {
        __syncthreads();
        *(float4*)&sAh[ar * 40 + ac]     = *(const float4*)(gAh + k0);
        *(float4*)&sAh[ar * 40 + ac + 8] = *(const float4*)(gAh + k0 + 8);
        *(float4*)&sAl[ar * 40 + ac]     = *(const float4*)(gAl + k0);
        *(float4*)&sAl[ar * 40 + ac + 8] = *(const float4*)(gAl + k0 + 8);
        *(float4*)&sBh[br * 40 + bc]     = *(const float4*)(gBh + k0);
        *(float4*)&sBl[br * 40 + bc]     = *(const float4*)(gBl + k0);
        __syncthreads();

        bf16x8 ah[4], al[4], bh[2], bl[2];
#pragma unroll
        for (int rt = 0; rt < 4; rt++) {
            int r = wr * 64 + rt * 16 + am;
            ah[rt] = *(const bf16x8*)&sAh[r * 40 + qk];
            al[rt] = *(const bf16x8*)&sAl[r * 40 + qk];
        }
#pragma unroll
        for (int ct = 0; ct < 2; ct++) {
            int c = ct * 32 + wc * 16 + am;      // remapped: rope pair in-reg
            bh[ct] = *(const bf16x8*)&sBh[c * 40 + qk];
            bl[ct] = *(const bf16x8*)&sBl[c * 40 + qk];
        }
#pragma unroll
        for (int rt = 0; rt < 4; rt++)
#pragma unroll
            for (int ct = 0; ct < 2; ct++) {
                acc[rt][ct] = __builtin_amdgcn_mfma_f32_16x16x32_bf16(ah[rt], bh[ct], acc[rt][ct], 0, 0, 0);
                acc[rt][ct] = __builtin_amdgcn_mfma_f32_16x16x32_bf16(ah[rt], bl[ct], acc[rt][ct], 0, 0, 0);
                acc[rt][ct] = __builtin_amdgcn_mfma_f32_16x16x32_bf16(al[rt], bh[ct], acc[rt][ct], 0, 0, 0);
            }
    }

    int sec  = blockIdx.x >> 4;        // 0=q, 1=k, 2=v
    int hd   = blockIdx.x & 15;
    int d_lo = wc * 16 + am;           // 0..31
    float b1 = bias[col0 + d_lo];
    float b2 = bias[col0 + 32 + d_lo];
    int rq = (lane >> 4) * 4;
#pragma unroll
    for (int rt = 0; rt < 4; rt++)
#pragma unroll
        for (int rg = 0; rg < 4; rg++) {
            int row = row0 + wr * 64 + rt * 16 + rq + rg;
            float x1 = acc[rt][0][rg] + b1;
            float x2 = acc[rt][1][rg] + b2;
            float o1, o2;
            if (sec < 2) {
                float cs = cost[row * 32 + d_lo];
                float sn = sint[row * 32 + d_lo];
                o1 = x1 * cs - x2 * sn;
                o2 = x2 * cs + x1 * sn;
                if (sec == 0) { o1 *= 0.125f; o2 *= 0.125f; }
            } else {
                o1 = x1; o2 = x2;
            }
            size_t base = (size_t)row * 3072 + sec * 1024 + hd * 64 + d_lo;
            unsigned short h1 = f2bf(o1);
            qkvh[base] = h1;       qkvl[base] = f2bf(o1 - bf2f(h1));
            unsigned short h2 = f2bf(o2);
            qkvh[base + 32] = h2;  qkvl[base + 32] = f2bf(o2 - bf2f(h2));
        }
}

// ---------------------------------------------------------------------------
// bf16x3 MFMA GEMM, 64x64 tile, BK=64 (gemm1 N=512 split epilogue, p_d N=256).
// ---------------------------------------------------------------------------
__global__ __launch_bounds__(256) void gemm64_bf16x3(
    const unsigned short* __restrict__ Ah, const unsigned short* __restrict__ Al,
    const unsigned short* __restrict__ Bh, const unsigned short* __restrict__ Bl,
    const float* __restrict__ bias_lo, const float* __restrict__ bias_hi,
    float* __restrict__ Cf, unsigned short* __restrict__ Chi,
    unsigned short* __restrict__ Clo, int M, int N, int Kd, int split_col)
{
    __shared__ unsigned short sAh[64 * 72], sAl[64 * 72];
    __shared__ unsigned short sBh[64 * 72], sBl[64 * 72];
    int tid = threadIdx.x;
    int lane = tid & 63, wv = tid >> 6;
    int wr = wv >> 1, wc = wv & 1;          // wave 32x32
    int row0 = blockIdx.y * 64, col0 = blockIdx.x * 64;

    f32x4 acc[2][2];
#pragma unroll
    for (int i = 0; i < 2; i++)
#pragma unroll
        for (int j = 0; j < 2; j++) acc[i][j] = (f32x4){0.f, 0.f, 0.f, 0.f};

    int sr = tid >> 2, sc = (tid & 3) * 16;   // row, 16-elem chunk of 64
    const unsigned short* gAh = Ah + (size_t)(row0 + sr) * Kd + sc;
    const unsigned short* gAl = Al + (size_t)(row0 + sr) * Kd + sc;
    const unsigned short* gBh = Bh + (size_t)(col0 + sr) * Kd + sc;
    const unsigned short* gBl = Bl + (size_t)(col0 + sr) * Kd + sc;
    int am = lane & 15, qk = (lane >> 4) * 8;

    for (int k0 = 0; k0 < Kd; k0 += 64) {
        __syncthreads();
        *(float4*)&sAh[sr * 72 + sc]     = *(const float4*)(gAh + k0);
        *(float4*)&sAh[sr * 72 + sc + 8] = *(const float4*)(gAh + k0 + 8);
        *(float4*)&sAl[sr * 72 + sc]     = *(const float4*)(gAl + k0);
        *(float4*)&sAl[sr * 72 + sc + 8] = *(const float4*)(gAl + k0 + 8);
        *(float4*)&sBh[sr * 72 + sc]     = *(const float4*)(gBh + k0);
        *(float4*)&sBh[sr * 72 + sc + 8] = *(const float4*)(gBh + k0 + 8);
        *(float4*)&sBl[sr * 72 + sc]     = *(const float4*)(gBl + k0);
        *(float4*)&sBl[sr * 72 + sc + 8] = *(const float4*)(gBl + k0 + 8);
        __syncthreads();

#pragma unroll
        for (int ks = 0; ks < 2; ks++) {
            bf16x8 ah[2], al[2], bh[2], bl[2];
#pragma unroll
            for (int rt = 0; rt < 2; rt++) {
                int r = wr * 32 + rt * 16 + am;
                ah[rt] = *(const bf16x8*)&sAh[r * 72 + ks * 32 + qk];
                al[rt] = *(const bf16x8*)&sAl[r * 72 + ks * 32 + qk];
            }
#pragma unroll
            for (int ct = 0; ct < 2; ct++) {
                int c = wc * 32 + ct * 16 + am;
                bh[ct] = *(const bf16x8*)&sBh[c * 72 + ks * 32 + qk];
                bl[ct] = *(const bf16x8*)&sBl[c * 72 + ks * 32 + qk];
            }
#pragma unroll
            for (int rt = 0; rt < 2; rt++)
#pragma unroll
                for (int ct = 0; ct < 2; ct++) {
                    acc[rt][ct] = __builtin_amdgcn_mfma_f32_16x16x32_bf16(ah[rt], bh[ct], acc[rt][ct], 0, 0, 0);
                    acc[rt][ct] = __builtin_amdgcn_mfma_f32_16x16x32_bf16(ah[rt], bl[ct], acc[rt][ct], 0, 0, 0);
                    acc[rt][ct] = __builtin_amdgcn_mfma_f32_16x16x32_bf16(al[rt], bh[ct], acc[rt][ct], 0, 0, 0);
                }
        }
    }

    int rq = (lane >> 4) * 4;
#pragma unroll
    for (int rt = 0; rt < 2; rt++)
#pragma unroll
        for (int ct = 0; ct < 2; ct++) {
            int col = col0 + wc * 32 + ct * 16 + am;
#pragma unroll
            for (int rg = 0; rg < 4; rg++) {
                int row = row0 + wr * 32 + rt * 16 + rq + rg;
                float v = acc[rt][ct][rg];
                if (col < split_col) {
                    if (bias_lo) v += bias_lo[col];
                    size_t idx = (size_t)row * split_col + col;
                    unsigned short hh = f2bf(v);
                    Chi[idx] = hh;
                    Clo[idx] = f2bf(v - bf2f(hh));
                } else {
                    if (bias_hi) v += bias_hi[col - split_col];
                    Cf[(size_t)row * (N - split_col) + col - split_col] = v;
                }
            }
        }
}

// ---------------------------------------------------------------------------
// Fused index scores + top-K membership (R5-exact: R0's 4-rows/block compute
// loop, 64x132 tile, 16 staging barriers; barrier-free radix).
// ---------------------------------------------------------------------------
__global__ __launch_bounds__(256) void score_topk_kernel(
    const float* __restrict__ qIk,
    const int* __restrict__ coords, const float* __restrict__ rpe_table,
    const float* __restrict__ W1g, const float* __restrict__ b1g,
    const float* __restrict__ W2g, const float* __restrict__ b2g,
    unsigned* __restrict__ selmask)
{
    __shared__ float skI[64][132];
    __shared__ float sqI2[4][IDH2_];
    __shared__ unsigned skeys[4][LI_];
    __shared__ int shist[4][256];
    __shared__ float srpe[NBUCK_ * IH_];
    __shared__ float sW1[GH_ * IH_], sb1[GH_], sW2[IH_ * GH_], sb2[IH_];

    int tid  = threadIdx.x;
    int lane = tid & 63;
    int wv   = tid >> 6;
    int row  = blockIdx.x * 4 + wv;
    int n    = (blockIdx.x * 4) >> 9;

    for (int i = tid; i < NBUCK_ * IH_; i += 256) srpe[i] = rpe_table[i];
    if (tid < 32) sW1[tid] = W1g[tid];
    else if (tid < 64) sW2[tid - 32] = W2g[tid - 32];
    else if (tid < 72) sb1[tid - 64] = b1g[tid - 64];
    else if (tid < 76) sb2[tid - 72] = b2g[tid - 72];
    for (int i = tid; i < 4 * IDH2_; i += 256)
        sqI2[i >> 7][i & 127] =
            qIk[(size_t)(blockIdx.x * 4 + (i >> 7)) * 256 + (i & 127)];
    int pq = coords[row * 2 + 1];

    for (int kt = 0; kt < 8; kt++) {
        __syncthreads();
        {
            int r  = tid >> 2;
            int d0 = (tid & 3) * 32;
            const float* src = qIk + (size_t)(n * LI_ + kt * 64 + r) * 256 + 128 + d0;
#pragma unroll
            for (int j = 0; j < 8; j++)
                *(float4*)&skI[r][d0 + j * 4] = *(const float4*)(src + j * 4);
        }
        __syncthreads();

        int kloc = lane;
        int kg   = kt * 64 + kloc;
        const float* sq = &sqI2[wv][0];
        float dh[8];
#pragma unroll
        for (int hh = 0; hh < 8; hh++) {
            float acc = 0.0f;
#pragma unroll
            for (int d = 0; d < 16; d += 4) {
                float4 kv = *(const float4*)&skI[kloc][hh * 16 + d];
                acc += sq[hh * 16 + d + 0] * kv.x + sq[hh * 16 + d + 1] * kv.y +
                       sq[hh * 16 + d + 2] * kv.z + sq[hh * 16 + d + 3] * kv.w;
            }
            dh[hh] = acc;
        }
        int pk = coords[(n * LI_ + kg) * 2 + 1];
        int rel = pq - pk;
        rel = rel < -MAXREL_ ? -MAXREL_ : (rel > MAXREL_ ? MAXREL_ : rel);
        const float* rp = srpe + (rel + MAXREL_) * IH_;
        float t1[GH_];
#pragma unroll
        for (int g = 0; g < GH_; g++) t1[g] = sb1[g];
#pragma unroll
        for (int j = 0; j < IH_; j++) {
            float gate = dh[IH_ + j] + rp[j];
#pragma unroll
            for (int g = 0; g < GH_; g++) t1[g] += gate * sW1[g * IH_ + j];
        }
#pragma unroll
        for (int g = 0; g < GH_; g++) t1[g] = fmaxf(t1[g], 0.0f);
        float score = 0.0f;
#pragma unroll
        for (int j = 0; j < IH_; j++) {
            float t2 = sb2[j];
#pragma unroll
            for (int g = 0; g < GH_; g++) t2 += t1[g] * sW2[j * GH_ + g];
            float sg = 1.0f / (1.0f + expf(-t2));
            float rs = fmaxf(dh[j] + rp[j], 0.0f);
            score += rs * sg;
        }
        unsigned bits = __float_as_uint(score);
        skeys[wv][kg] = (bits & 0x80000000u) ? ~bits : (bits | 0x80000000u);
    }
    // no barrier: skeys[wv]/shist[wv] per-wave; same-wave DS ops in-order

    unsigned pref = 0u;
    int kcur = K_;
    const unsigned himask[4] = {0u, 0xFF000000u, 0xFFFF0000u, 0xFFFFFF00u};
#pragma unroll
    for (int pass = 0; pass < 4; pass++) {
        int shift = 24 - pass * 8;
        unsigned hm = himask[pass];
        *(int4*)&shist[wv][4 * lane] = make_int4(0, 0, 0, 0);
#pragma unroll
        for (int c = 0; c < 8; c++) {
            unsigned key = skeys[wv][c * 64 + lane];
            if ((key & hm) == pref) atomicAdd(&shist[wv][(key >> shift) & 255], 1);
        }
        int4 b4 = *(const int4*)&shist[wv][4 * lane];
        int b[4] = {b4.x, b4.y, b4.z, b4.w};
        int t = b[0] + b[1] + b[2] + b[3];
        int Ssum = t;
#pragma unroll
        for (int off = 1; off < 64; off <<= 1) {
            int u = __shfl_down(Ssum, off, 64);
            if (lane + off < 64) Ssum += u;
        }
        int E = Ssum - t;
        int cs[5];
        cs[4] = E;
        cs[3] = b[3] + E;
        cs[2] = b[2] + cs[3];
        cs[1] = b[1] + cs[2];
        cs[0] = b[0] + cs[1];
        bool found = false;
        unsigned cpref = 0u; int ck = 0;
#pragma unroll
        for (int j = 0; j < 4; j++) {
            if (!found && cs[j] >= kcur && cs[j + 1] < kcur) {
                found = true;
                cpref = pref | ((unsigned)(4 * lane + j) << shift);
                ck = kcur - cs[j + 1];
            }
        }
        unsigned long long bm = __ballot(found);
        int src = __ffsll((long long)bm) - 1;
        pref = (unsigned)__shfl((int)cpref, src, 64);
        kcur = __shfl(ck, src, 64);
    }
    unsigned Tu = pref;

    unsigned long long bg[8], be[8];
#pragma unroll
    for (int c = 0; c < 8; c++) {
        unsigned key = skeys[wv][c * 64 + lane];
        bg[c] = __ballot(key > Tu);
        be[c] = __ballot(key == Tu);
    }
    if (lane < 16) {
        int total_gt = 0;
#pragma unroll
        for (int c = 0; c < 8; c++) total_gt += __popcll(bg[c]);
        int base = 0;
#pragma unroll
        for (int c = 0; c < 8; c++) {
            if (2 * c < lane)     base += __popc((unsigned)be[c]);
            if (2 * c + 1 < lane) base += __popc((unsigned)(be[c] >> 32));
        }
        unsigned gw = (unsigned)(bg[lane >> 1] >> (32 * (lane & 1)));
        unsigned ew = (unsigned)(be[lane >> 1] >> (32 * (lane & 1)));
        int ne = K_ - total_gt - base;
        int pc = __popc(ew);
        int m = ne < 0 ? 0 : (ne > pc ? pc : ne);
        while (pc > m) { ew ^= (1u << (31 - __clz(ew))); pc--; }
        selmask[(size_t)row * 16 + lane] = gw | ew;
    }
}

// ---------------------------------------------------------------------------
// Dense-masked attention v7 (R7-exact): T14 async-STAGE prefetch, Q frags
// hoisted, setprio around MFMA clusters, separate P buffer, 2 barriers/kt.
// ---------------------------------------------------------------------------
__global__ __launch_bounds__(256) void attn_kernel(
    const unsigned short* __restrict__ qkvh, const unsigned short* __restrict__ qkvl,
    const unsigned* __restrict__ selmask,
    unsigned short* __restrict__ outh, unsigned short* __restrict__ outl)
{
    __shared__ unsigned short Qh[64 * 72],  Ql[64 * 72];   // [q][d]
    __shared__ unsigned short Kh[64 * 72],  Kl[64 * 72];   // [key][d]
    __shared__ unsigned short VTh[64 * 72], VTl[64 * 72];  // V^T [d][key]
    __shared__ unsigned short Ph[64 * 72],  Pl[64 * 72];   // P [q][key]
    __shared__ unsigned Ms[64][16];

    int b  = blockIdx.x;
    int qt = b >> 6;                 // XCD swizzle: qt in high bits
    int nh = b & 63;
    int h  = nh & 15;
    int n  = nh >> 4;
    int tid = threadIdx.x;
    int lane = tid & 63, w = tid >> 6;
    int lane15 = lane & 15, quad = lane >> 4;
    int q0 = n * LI_ + qt * 64;

    for (int i = tid; i < 64 * 16; i += 256)
        Ms[i >> 4][i & 15] = selmask[(size_t)(q0 + (i >> 4)) * 16 + (i & 15)];

    // stage Q once (already rope'd, scaled, split)
    {
        int r = tid >> 2, c0 = (tid & 3) * 16;
        size_t off = (size_t)(q0 + r) * 3072 + h * 64 + c0;
        *(uint4*)&Qh[r * 72 + c0]     = *(const uint4*)(qkvh + off);
        *(uint4*)&Qh[r * 72 + c0 + 8] = *(const uint4*)(qkvh + off + 8);
        *(uint4*)&Ql[r * 72 + c0]     = *(const uint4*)(qkvl + off);
        *(uint4*)&Ql[r * 72 + c0 + 8] = *(const uint4*)(qkvl + off + 8);
    }
    __syncthreads();   // Q staged -> hoist fragments to registers once
    bf16x8 qfh[2], qfl[2];
#pragma unroll
    for (int ks = 0; ks < 2; ks++) {
        qfh[ks] = *(const bf16x8*)&Qh[(16 * w + lane15) * 72 + ks * 32 + quad * 8];
        qfl[ks] = *(const bf16x8*)&Ql[(16 * w + lane15) * 72 + ks * 32 + quad * 8];
    }

    // prefetch addressing (constant per thread)
    int kr = tid >> 2, kc0 = (tid & 3) * 16;          // K stage coords
    int vd = lane, vk0 = w * 16;                      // V stage coords
    const size_t kbase = (size_t)n * LI_ * 3072 + 1024 + h * 64;
    const size_t vbase = (size_t)n * LI_ * 3072 + 2048 + h * 64;

    uint4 pkh0, pkh1, pkl0, pkl1;                     // K prefetch regs
    unsigned short pvh[16], pvl[16];                  // V prefetch regs

#define LOADT(KT)                                                              \
    {                                                                          \
        size_t offK = kbase + (size_t)((KT) * 64 + kr) * 3072 + kc0;           \
        pkh0 = *(const uint4*)(qkvh + offK);                                   \
        pkh1 = *(const uint4*)(qkvh + offK + 8);                               \
        pkl0 = *(const uint4*)(qkvl + offK);                                   \
        pkl1 = *(const uint4*)(qkvl + offK + 8);                               \
        size_t offV = vbase + (size_t)((KT) * 64 + vk0) * 3072 + vd;           \
        _Pragma("unroll")                                                      \
        for (int j = 0; j < 16; j++) {                                         \
            pvh[j] = qkvh[offV + (size_t)j * 3072];                            \
            pvl[j] = qkvl[offV + (size_t)j * 3072];                            \
        }                                                                      \
    }

    LOADT(0);

    f32x4 o_acc[4];
#pragma unroll
    for (int i = 0; i < 4; i++) o_acc[i] = (f32x4){0.f, 0.f, 0.f, 0.f};
    float rsum[4] = {};

    for (int kt = 0; kt < 8; kt++) {
        __syncthreads();   // prev iter's Kh (QK) and VTh (PV) reads done
        // reg -> LDS writes only (loads were issued last iteration)
        *(uint4*)&Kh[kr * 72 + kc0]      = pkh0;
        *(uint4*)&Kh[kr * 72 + kc0 + 8]  = pkh1;
        *(uint4*)&Kl[kr * 72 + kc0]      = pkl0;
        *(uint4*)&Kl[kr * 72 + kc0 + 8]  = pkl1;
        *(uint4*)&VTh[vd * 72 + vk0]     = *(uint4*)&pvh[0];
        *(uint4*)&VTh[vd * 72 + vk0 + 8] = *(uint4*)&pvh[8];
        *(uint4*)&VTl[vd * 72 + vk0]     = *(uint4*)&pvl[0];
        *(uint4*)&VTl[vd * 72 + vk0 + 8] = *(uint4*)&pvl[8];
        __syncthreads();   // stage visible to all waves

        // issue next tile's loads; latency hides under QK/softmax/PV
        if (kt < 7) LOADT(kt + 1);

        // QK: wave w computes q-tile w vs all 4 key-tiles, bf16x3
        f32x4 s_acc[4];
#pragma unroll
        for (int nt = 0; nt < 4; nt++) s_acc[nt] = (f32x4){0.f, 0.f, 0.f, 0.f};
        __builtin_amdgcn_s_setprio(1);
#pragma unroll
        for (int nt = 0; nt < 4; nt++) {
#pragma unroll
            for (int ks = 0; ks < 2; ks++) {
                bf16x8 kfh = *(const bf16x8*)&Kh[(16 * nt + lane15) * 72 + ks * 32 + quad * 8];
                bf16x8 kfl = *(const bf16x8*)&Kl[(16 * nt + lane15) * 72 + ks * 32 + quad * 8];
                s_acc[nt] = __builtin_amdgcn_mfma_f32_16x16x32_bf16(qfh[ks], kfh, s_acc[nt], 0, 0, 0);
                s_acc[nt] = __builtin_amdgcn_mfma_f32_16x16x32_bf16(qfh[ks], kfl, s_acc[nt], 0, 0, 0);
                s_acc[nt] = __builtin_amdgcn_mfma_f32_16x16x32_bf16(qfl[ks], kfh, s_acc[nt], 0, 0, 0);
            }
        }
        __builtin_amdgcn_s_setprio(0);

        // softmax + P split; writes only this wave's P rows -> no barrier
#pragma unroll
        for (int nt = 0; nt < 4; nt++) {
            int kb = kt * 64 + nt * 16 + lane15;
            int wi = kb >> 5, bit = kb & 31;
#pragma unroll
            for (int reg = 0; reg < 4; reg++) {
                int qloc = 16 * w + quad * 4 + reg;
                unsigned mw = Ms[qloc][wi];
                float p = ((mw >> bit) & 1u) ? __expf(s_acc[nt][reg]) : 0.0f;
                rsum[reg] += p;
                unsigned short ph = f2bf(p);
                Ph[qloc * 72 + nt * 16 + lane15] = ph;
                Pl[qloc * 72 + nt * 16 + lane15] = f2bf(p - bf2f(ph));
            }
        }

        // PV: A = P [q][key] (own rows), B = V^T [d][key], bf16x3
        {
            bf16x8 pfh[2], pfl[2];
#pragma unroll
            for (int ks = 0; ks < 2; ks++) {
                pfh[ks] = *(const bf16x8*)&Ph[(16 * w + lane15) * 72 + ks * 32 + quad * 8];
                pfl[ks] = *(const bf16x8*)&Pl[(16 * w + lane15) * 72 + ks * 32 + quad * 8];
            }
            __builtin_amdgcn_s_setprio(1);
#pragma unroll
            for (int dt = 0; dt < 4; dt++) {
#pragma unroll
                for (int ks = 0; ks < 2; ks++) {
                    bf16x8 vfh = *(const bf16x8*)&VTh[(16 * dt + lane15) * 72 + ks * 32 + quad * 8];
                    bf16x8 vfl = *(const bf16x8*)&VTl[(16 * dt + lane15) * 72 + ks * 32 + quad * 8];
                    o_acc[dt] = __builtin_amdgcn_mfma_f32_16x16x32_bf16(pfh[ks], vfh, o_acc[dt], 0, 0, 0);
                    o_acc[dt] = __builtin_amdgcn_mfma_f32_16x16x32_bf16(pfh[ks], vfl, o_acc[dt], 0, 0, 0);
                    o_acc[dt] = __builtin_amdgcn_mfma_f32_16x16x32_bf16(pfl[ks], vfh, o_acc[dt], 0, 0, 0);
                }
            }
            __builtin_amdgcn_s_setprio(0);
        }
    }
#undef LOADT

    // row sums: reduce over the 16 lanes (lane15) sharing each q row
#pragma unroll
    for (int reg = 0; reg < 4; reg++) {
        rsum[reg] += __shfl_xor(rsum[reg], 1, 64);
        rsum[reg] += __shfl_xor(rsum[reg], 2, 64);
        rsum[reg] += __shfl_xor(rsum[reg], 4, 64);
        rsum[reg] += __shfl_xor(rsum[reg], 8, 64);
    }

    // epilogue: normalize, split hi/lo, store
#pragma unroll
    for (int dt = 0; dt < 4; dt++) {
#pragma unroll
        for (int reg = 0; reg < 4; reg++) {
            float v = o_acc[dt][reg] / rsum[reg];
            size_t ob = (size_t)(q0 + 16 * w + quad * 4 + reg) * 1024 + h * 64 + 16 * dt + lane15;
            unsigned short hh = f2bf(v);
            outh[ob] = hh;
            outl[ob] = f2bf(v - bf2f(hh));
        }
    }
}

// ---------------------------------------------------------------------------
extern "C" void kernel_launch(void* const* d_in, const int* in_sizes, int n_in,
                              void* d_out, int out_size, void* d_ws, size_t ws_size,
                              hipStream_t stream)
{
    const float* hidden  = (const float*)d_in[0];
    const int*   coords  = (const int*)d_in[1];
    const float* rope    = (const float*)d_in[3];
    const float* Wq_idx  = (const float*)d_in[4];
    const float* Wk_idx  = (const float*)d_in[5];
    const float* W1g     = (const float*)d_in[6];
    const float* b1g     = (const float*)d_in[7];
    const float* W2g     = (const float*)d_in[8];
    const float* b2g     = (const float*)d_in[9];
    const float* rpe     = (const float*)d_in[10];
    const float* Wqkv_d  = (const float*)d_in[11];
    const float* bqkv_d  = (const float*)d_in[12];
    const float* Wqkv_u  = (const float*)d_in[13];
    const float* bqkv_u  = (const float*)d_in[14];
    const float* Wp_d    = (const float*)d_in[15];
    const float* bp_d    = (const float*)d_in[16];
    const float* Wp_u    = (const float*)d_in[17];
    const float* bp_u    = (const float*)d_in[18];
    const float* scaler  = (const float*)d_in[19];
    float* out = (float*)d_out;

    unsigned short* sp_hi  = (unsigned short*)d_ws;
    unsigned short* sp_lo  = sp_hi + NSPLIT_;
    unsigned short* mid_hi = sp_lo + NSPLIT_;
    unsigned short* mid_lo = mid_hi + (size_t)S_ * BOT_;
    float* qkv = (float*)(mid_lo + (size_t)S_ * BOT_);   // slot kept (unused)
    float* qIk = qkv + (size_t)S_ * 3 * DIM_;
    unsigned* selmask = (unsigned*)(qIk + (size_t)S_ * 256);
    unsigned short* qkvh = (unsigned short*)(selmask + (size_t)S_ * 16);
    unsigned short* qkvl = qkvh + (size_t)S_ * 3 * DIM_;
    float* cost = (float*)(qkvl + (size_t)S_ * 3 * DIM_);
    float* sint = cost + NTRIG_;

    // 0) split hidden + all weights into hi/lo bf16, precompute cos/sin
    split_all_kernel<<<((NSPLIT_ + NTRIG_) / 4 + 255) / 256, 256, 0, stream>>>(
        hidden, Wqkv_d, Wq_idx, Wk_idx, Wqkv_u, Wp_d, Wp_u, rope,
        sp_hi, sp_lo, cost, sint);

    // 1) fused gemm1: hidden @ [Wqkv_d;Wq;Wk]^T -> mid(hi/lo) + qIk(fp32)
    gemm64_bf16x3<<<dim3(512 / 64, S_ / 64), 256, 0, stream>>>(
        sp_hi, sp_lo, sp_hi + OFF_W1_, sp_lo + OFF_W1_,
        bqkv_d, nullptr, qIk, mid_hi, mid_lo, S_, 512, DIM_, 256);

    // 2) fused index scores + top-k membership (R5-exact, 4 rows/block)
    score_topk_kernel<<<S_ / 4, 256, 0, stream>>>(
        qIk, coords, rpe, W1g, b1g, W2g, b2g, selmask);

    // 3) qkv = mid @ Wqkv_u^T + b, fused RoPE (table cos/sin) + hi/lo split
    gemm_qkv_rope<<<dim3(3 * DIM_ / 64, S_ / 128), 256, 0, stream>>>(
        mid_hi, mid_lo, sp_hi + OFF_WQKVU_, sp_lo + OFF_WQKVU_,
        bqkv_u, cost, sint, qkvh, qkvl);

    // 4) MFMA attention (T14 prefetch; emits attout hi/lo into split slots)
    attn_kernel<<<NIMG_ * H_ * 8, 256, 0, stream>>>(qkvh, qkvl, selmask, sp_hi, sp_lo);

    // 5) mid2 = attout @ Wp_d^T + b (hi/lo)
    gemm64_bf16x3<<<dim3(BOT_ / 64, S_ / 64), 256, 0, stream>>>(
        sp_hi, sp_lo, sp_hi + OFF_WPD_, sp_lo + OFF_WPD_,
        bp_d, nullptr, nullptr, mid_hi, mid_lo, S_, BOT_, DIM_, BOT_);

    // 6) out = mid2 @ Wp_u^T + b, *scaler (fp32)
    gemm_bf16x3<<<dim3(DIM_ / 64, S_ / 128), 256, 0, stream>>>(
        mid_hi, mid_lo, sp_hi + OFF_WPU_, sp_lo + OFF_WPU_,
        bp_u, scaler, out, S_, DIM_, BOT_);
}

// Round 11
// 246.034 us; speedup vs baseline: 1.0691x; 1.0006x over previous
//
#include <hip/hip_runtime.h>
#include <hip/hip_bf16.h>

// Problem constants
#define S_    2048
#define DIM_  1024
#define H_    16
#define DH_   64
#define BOT_  256
#define NIMG_ 4
#define LI_   512
#define K_    256
#define IH_   4
#define ID_   16
#define MAXREL_ 64
#define NBUCK_ 129
#define GH_   8
#define IDH2_ 128   // 2*IH*ID

typedef short bf16x8 __attribute__((ext_vector_type(8)));
typedef float f32x4  __attribute__((ext_vector_type(4)));

__device__ __forceinline__ unsigned short f2bf(float x) {   // RNE float->bf16
    unsigned u = __float_as_uint(x);
    return (unsigned short)((u + 0x7fffu + ((u >> 16) & 1u)) >> 16);
}
__device__ __forceinline__ float bf2f(unsigned short h) {
    return __uint_as_float(((unsigned)h) << 16);
}

// Split-region element offsets (ushort units). W1 = [Wqkv_d;Wq;Wk] contiguous.
#define OFF_W1_    2097152
#define OFF_WQ_    2359296
#define OFF_WK_    2490368
#define OFF_WQKVU_ 2621440
#define OFF_WPD_   3407872
#define OFF_WPU_   3670016
#define NSPLIT_    3932160
#define NTRIG_     65536      // S_*32 cos/sin table entries

// ---------------------------------------------------------------------------
// Fused hi/lo bf16 split of hidden + all 6 weight matrices + cos/sin tables.
// ---------------------------------------------------------------------------
__global__ __launch_bounds__(256) void split_all_kernel(
    const float* __restrict__ hid, const float* __restrict__ wqd,
    const float* __restrict__ wq,  const float* __restrict__ wk,
    const float* __restrict__ wqu, const float* __restrict__ wpd,
    const float* __restrict__ wpu, const float* __restrict__ rope,
    unsigned short* __restrict__ hi, unsigned short* __restrict__ lo,
    float* __restrict__ cost, float* __restrict__ sint)
{
    long e = ((long)blockIdx.x * 256 + threadIdx.x) * 4;
    if (e >= NSPLIT_ + NTRIG_) return;
    if (e >= NSPLIT_) {                      // trig-table segment
        long t = e - NSPLIT_;
        float4 r = *(const float4*)(rope + t);
        float4 c, s;
        c.x = cosf(r.x); s.x = sinf(r.x);
        c.y = cosf(r.y); s.y = sinf(r.y);
        c.z = cosf(r.z); s.z = sinf(r.z);
        c.w = cosf(r.w); s.w = sinf(r.w);
        *(float4*)&cost[t] = c;
        *(float4*)&sint[t] = s;
        return;
    }
    const float* src; long off;
    if (e < OFF_W1_)         { src = hid; off = 0; }
    else if (e < OFF_WQ_)    { src = wqd; off = OFF_W1_; }
    else if (e < OFF_WK_)    { src = wq;  off = OFF_WQ_; }
    else if (e < OFF_WQKVU_) { src = wk;  off = OFF_WK_; }
    else if (e < OFF_WPD_)   { src = wqu; off = OFF_WQKVU_; }
    else if (e < OFF_WPU_)   { src = wpd; off = OFF_WPD_; }
    else                     { src = wpu; off = OFF_WPU_; }
    float4 v = *(const float4*)(src + (e - off));
    ushort4 h, l;
    h.x = f2bf(v.x); l.x = f2bf(v.x - bf2f(h.x));
    h.y = f2bf(v.y); l.y = f2bf(v.y - bf2f(h.y));
    h.z = f2bf(v.z); l.z = f2bf(v.z - bf2f(h.z));
    h.w = f2bf(v.w); l.w = f2bf(v.w - bf2f(h.w));
    *(ushort4*)&hi[e] = h;
    *(ushort4*)&lo[e] = l;
}

// ---------------------------------------------------------------------------
// bf16x3 MFMA GEMM, 128x64 tile (large-N: p_u). fp32 out. (unchanged)
// ---------------------------------------------------------------------------
__global__ __launch_bounds__(256) void gemm_bf16x3(
    const unsigned short* __restrict__ Ah, const unsigned short* __restrict__ Al,
    const unsigned short* __restrict__ Bh, const unsigned short* __restrict__ Bl,
    const float* __restrict__ bias, const float* __restrict__ scale_ptr,
    float* __restrict__ Cf, int M, int N, int Kd)
{
    __shared__ unsigned short sAh[128 * 40], sAl[128 * 40];
    __shared__ unsigned short sBh[64 * 40],  sBl[64 * 40];
    int tid = threadIdx.x;
    int lane = tid & 63, wv = tid >> 6;
    int wr = wv >> 1, wc = wv & 1;
    int row0 = blockIdx.y * 128, col0 = blockIdx.x * 64;

    f32x4 acc[4][2];
#pragma unroll
    for (int i = 0; i < 4; i++)
#pragma unroll
        for (int j = 0; j < 2; j++) acc[i][j] = (f32x4){0.f, 0.f, 0.f, 0.f};

    int ar = tid >> 1, ac = (tid & 1) * 16;
    int br = tid >> 2, bc = (tid & 3) * 8;
    const unsigned short* gAh = Ah + (size_t)(row0 + ar) * Kd + ac;
    const unsigned short* gAl = Al + (size_t)(row0 + ar) * Kd + ac;
    const unsigned short* gBh = Bh + (size_t)(col0 + br) * Kd + bc;
    const unsigned short* gBl = Bl + (size_t)(col0 + br) * Kd + bc;
    int am = lane & 15, qk = (lane >> 4) * 8;

    for (int k0 = 0; k0 < Kd; k0 += 32) {
        __syncthreads();
        *(float4*)&sAh[ar * 40 + ac]     = *(const float4*)(gAh + k0);
        *(float4*)&sAh[ar * 40 + ac + 8] = *(const float4*)(gAh + k0 + 8);
        *(float4*)&sAl[ar * 40 + ac]     = *(const float4*)(gAl + k0);
        *(float4*)&sAl[ar * 40 + ac + 8] = *(const float4*)(gAl + k0 + 8);
        *(float4*)&sBh[br * 40 + bc]     = *(const float4*)(gBh + k0);
        *(float4*)&sBl[br * 40 + bc]     = *(const float4*)(gBl + k0);
        __syncthreads();

        bf16x8 ah[4], al[4], bh[2], bl[2];
#pragma unroll
        for (int rt = 0; rt < 4; rt++) {
            int r = wr * 64 + rt * 16 + am;
            ah[rt] = *(const bf16x8*)&sAh[r * 40 + qk];
            al[rt] = *(const bf16x8*)&sAl[r * 40 + qk];
        }
#pragma unroll
        for (int ct = 0; ct < 2; ct++) {
            int c = wc * 32 + ct * 16 + am;
            bh[ct] = *(const bf16x8*)&sBh[c * 40 + qk];
            bl[ct] = *(const bf16x8*)&sBl[c * 40 + qk];
        }
#pragma unroll
        for (int rt = 0; rt < 4; rt++)
#pragma unroll
            for (int ct = 0; ct < 2; ct++) {
                acc[rt][ct] = __builtin_amdgcn_mfma_f32_16x16x32_bf16(ah[rt], bh[ct], acc[rt][ct], 0, 0, 0);
                acc[rt][ct] = __builtin_amdgcn_mfma_f32_16x16x32_bf16(ah[rt], bl[ct], acc[rt][ct], 0, 0, 0);
                acc[rt][ct] = __builtin_amdgcn_mfma_f32_16x16x32_bf16(al[rt], bh[ct], acc[rt][ct], 0, 0, 0);
            }
    }

    float scl = scale_ptr ? *scale_ptr : 1.0f;
    int rq = (lane >> 4) * 4;
#pragma unroll
    for (int rt = 0; rt < 4; rt++)
#pragma unroll
        for (int ct = 0; ct < 2; ct++) {
            int col = col0 + wc * 32 + ct * 16 + am;
            float bz = bias ? bias[col] : 0.0f;
#pragma unroll
            for (int rg = 0; rg < 4; rg++) {
                int row = row0 + wr * 64 + rt * 16 + rq + rg;
                Cf[(size_t)row * N + col] = (acc[rt][ct][rg] + bz) * scl;
            }
        }
}

// ---------------------------------------------------------------------------
// gemm_qkv_rope: fused gemm2 + RoPE (table cos/sin) + hi/lo split (R10-exact).
// ---------------------------------------------------------------------------
__global__ __launch_bounds__(256) void gemm_qkv_rope(
    const unsigned short* __restrict__ Ah, const unsigned short* __restrict__ Al,
    const unsigned short* __restrict__ Bh, const unsigned short* __restrict__ Bl,
    const float* __restrict__ bias, const float* __restrict__ cost,
    const float* __restrict__ sint,
    unsigned short* __restrict__ qkvh, unsigned short* __restrict__ qkvl)
{
    __shared__ unsigned short sAh[128 * 40], sAl[128 * 40];
    __shared__ unsigned short sBh[64 * 40],  sBl[64 * 40];
    int tid = threadIdx.x;
    int lane = tid & 63, wv = tid >> 6;
    int wr = wv >> 1, wc = wv & 1;
    int row0 = blockIdx.y * 128, col0 = blockIdx.x * 64;
    const int Kd = BOT_;

    f32x4 acc[4][2];
#pragma unroll
    for (int i = 0; i < 4; i++)
#pragma unroll
        for (int j = 0; j < 2; j++) acc[i][j] = (f32x4){0.f, 0.f, 0.f, 0.f};

    int ar = tid >> 1, ac = (tid & 1) * 16;
    int br = tid >> 2, bc = (tid & 3) * 8;
    const unsigned short* gAh = Ah + (size_t)(row0 + ar) * Kd + ac;
    const unsigned short* gAl = Al + (size_t)(row0 + ar) * Kd + ac;
    const unsigned short* gBh = Bh + (size_t)(col0 + br) * Kd + bc;
    const unsigned short* gBl = Bl + (size_t)(col0 + br) * Kd + bc;
    int am = lane & 15, qk = (lane >> 4) * 8;

    for (int k0 = 0; k0 < Kd; k0 += 32) {
        __syncthreads();
        *(float4*)&sAh[ar * 40 + ac]     = *(const float4*)(gAh + k0);
        *(float4*)&sAh[ar * 40 + ac + 8] = *(const float4*)(gAh + k0 + 8);
        *(float4*)&sAl[ar * 40 + ac]     = *(const float4*)(gAl + k0);
        *(float4*)&sAl[ar * 40 + ac + 8] = *(const float4*)(gAl + k0 + 8);
        *(float4*)&sBh[br * 40 + bc]     = *(const float4*)(gBh + k0);
        *(float4*)&sBl[br * 40 + bc]     = *(const float4*)(gBl + k0);
        __syncthreads();

        bf16x8 ah[4], al[4], bh[2], bl[2];
#pragma unroll
        for (int rt = 0; rt < 4; rt++) {
            int r = wr * 64 + rt * 16 + am;
            ah[rt] = *(const bf16x8*)&sAh[r * 40 + qk];
            al[rt] = *(const bf16x8*)&sAl[r * 40 + qk];
        }
#pragma unroll
        for (int ct = 0; ct < 2; ct++) {
            int c = ct * 32 + wc * 16 + am;      // remapped: rope pair in-reg
            bh[ct] = *(const bf16x8*)&sBh[c * 40 + qk];
            bl[ct] = *(const bf16x8*)&sBl[c * 40 + qk];
        }
#pragma unroll
        for (int rt = 0; rt < 4; rt++)
#pragma unroll
            for (int ct = 0; ct < 2; ct++) {
                acc[rt][ct] = __builtin_amdgcn_mfma_f32_16x16x32_bf16(ah[rt], bh[ct], acc[rt][ct], 0, 0, 0);
                acc[rt][ct] = __builtin_amdgcn_mfma_f32_16x16x32_bf16(ah[rt], bl[ct], acc[rt][ct], 0, 0, 0);
                acc[rt][ct] = __builtin_amdgcn_mfma_f32_16x16x32_bf16(al[rt], bh[ct], acc[rt][ct], 0, 0, 0);
            }
    }

    int sec  = blockIdx.x >> 4;        // 0=q, 1=k, 2=v
    int hd   = blockIdx.x & 15;
    int d_lo = wc * 16 + am;           // 0..31
    float b1 = bias[col0 + d_lo];
    float b2 = bias[col0 + 32 + d_lo];
    int rq = (lane >> 4) * 4;
#pragma unroll
    for (int rt = 0; rt < 4; rt++)
#pragma unroll
        for (int rg = 0; rg < 4; rg++) {
            int row = row0 + wr * 64 + rt * 16 + rq + rg;
            float x1 = acc[rt][0][rg] + b1;
            float x2 = acc[rt][1][rg] + b2;
            float o1, o2;
            if (sec < 2) {
                float cs = cost[row * 32 + d_lo];
                float sn = sint[row * 32 + d_lo];
                o1 = x1 * cs - x2 * sn;
                o2 = x2 * cs + x1 * sn;
                if (sec == 0) { o1 *= 0.125f; o2 *= 0.125f; }
            } else {
                o1 = x1; o2 = x2;
            }
            size_t base = (size_t)row * 3072 + sec * 1024 + hd * 64 + d_lo;
            unsigned short h1 = f2bf(o1);
            qkvh[base] = h1;       qkvl[base] = f2bf(o1 - bf2f(h1));
            unsigned short h2 = f2bf(o2);
            qkvh[base + 32] = h2;  qkvl[base + 32] = f2bf(o2 - bf2f(h2));
        }
}

// ---------------------------------------------------------------------------
// bf16x3 MFMA GEMM, 64x64 tile, BK=64 (gemm1 N=512 split epilogue, p_d N=256).
// ---------------------------------------------------------------------------
__global__ __launch_bounds__(256) void gemm64_bf16x3(
    const unsigned short* __restrict__ Ah, const unsigned short* __restrict__ Al,
    const unsigned short* __restrict__ Bh, const unsigned short* __restrict__ Bl,
    const float* __restrict__ bias_lo, const float* __restrict__ bias_hi,
    float* __restrict__ Cf, unsigned short* __restrict__ Chi,
    unsigned short* __restrict__ Clo, int M, int N, int Kd, int split_col)
{
    __shared__ unsigned short sAh[64 * 72], sAl[64 * 72];
    __shared__ unsigned short sBh[64 * 72], sBl[64 * 72];
    int tid = threadIdx.x;
    int lane = tid & 63, wv = tid >> 6;
    int wr = wv >> 1, wc = wv & 1;          // wave 32x32
    int row0 = blockIdx.y * 64, col0 = blockIdx.x * 64;

    f32x4 acc[2][2];
#pragma unroll
    for (int i = 0; i < 2; i++)
#pragma unroll
        for (int j = 0; j < 2; j++) acc[i][j] = (f32x4){0.f, 0.f, 0.f, 0.f};

    int sr = tid >> 2, sc = (tid & 3) * 16;   // row, 16-elem chunk of 64
    const unsigned short* gAh = Ah + (size_t)(row0 + sr) * Kd + sc;
    const unsigned short* gAl = Al + (size_t)(row0 + sr) * Kd + sc;
    const unsigned short* gBh = Bh + (size_t)(col0 + sr) * Kd + sc;
    const unsigned short* gBl = Bl + (size_t)(col0 + sr) * Kd + sc;
    int am = lane & 15, qk = (lane >> 4) * 8;

    for (int k0 = 0; k0 < Kd; k0 += 64) {
        __syncthreads();
        *(float4*)&sAh[sr * 72 + sc]     = *(const float4*)(gAh + k0);
        *(float4*)&sAh[sr * 72 + sc + 8] = *(const float4*)(gAh + k0 + 8);
        *(float4*)&sAl[sr * 72 + sc]     = *(const float4*)(gAl + k0);
        *(float4*)&sAl[sr * 72 + sc + 8] = *(const float4*)(gAl + k0 + 8);
        *(float4*)&sBh[sr * 72 + sc]     = *(const float4*)(gBh + k0);
        *(float4*)&sBh[sr * 72 + sc + 8] = *(const float4*)(gBh + k0 + 8);
        *(float4*)&sBl[sr * 72 + sc]     = *(const float4*)(gBl + k0);
        *(float4*)&sBl[sr * 72 + sc + 8] = *(const float4*)(gBl + k0 + 8);
        __syncthreads();

#pragma unroll
        for (int ks = 0; ks < 2; ks++) {
            bf16x8 ah[2], al[2], bh[2], bl[2];
#pragma unroll
            for (int rt = 0; rt < 2; rt++) {
                int r = wr * 32 + rt * 16 + am;
                ah[rt] = *(const bf16x8*)&sAh[r * 72 + ks * 32 + qk];
                al[rt] = *(const bf16x8*)&sAl[r * 72 + ks * 32 + qk];
            }
#pragma unroll
            for (int ct = 0; ct < 2; ct++) {
                int c = wc * 32 + ct * 16 + am;
                bh[ct] = *(const bf16x8*)&sBh[c * 72 + ks * 32 + qk];
                bl[ct] = *(const bf16x8*)&sBl[c * 72 + ks * 32 + qk];
            }
#pragma unroll
            for (int rt = 0; rt < 2; rt++)
#pragma unroll
                for (int ct = 0; ct < 2; ct++) {
                    acc[rt][ct] = __builtin_amdgcn_mfma_f32_16x16x32_bf16(ah[rt], bh[ct], acc[rt][ct], 0, 0, 0);
                    acc[rt][ct] = __builtin_amdgcn_mfma_f32_16x16x32_bf16(ah[rt], bl[ct], acc[rt][ct], 0, 0, 0);
                    acc[rt][ct] = __builtin_amdgcn_mfma_f32_16x16x32_bf16(al[rt], bh[ct], acc[rt][ct], 0, 0, 0);
                }
        }
    }

    int rq = (lane >> 4) * 4;
#pragma unroll
    for (int rt = 0; rt < 2; rt++)
#pragma unroll
        for (int ct = 0; ct < 2; ct++) {
            int col = col0 + wc * 32 + ct * 16 + am;
#pragma unroll
            for (int rg = 0; rg < 4; rg++) {
                int row = row0 + wr * 32 + rt * 16 + rq + rg;
                float v = acc[rt][ct][rg];
                if (col < split_col) {
                    if (bias_lo) v += bias_lo[col];
                    size_t idx = (size_t)row * split_col + col;
                    unsigned short hh = f2bf(v);
                    Chi[idx] = hh;
                    Clo[idx] = f2bf(v - bf2f(hh));
                } else {
                    if (bias_hi) v += bias_hi[col - split_col];
                    Cf[(size_t)row * (N - split_col) + col - split_col] = v;
                }
            }
        }
}

// ---------------------------------------------------------------------------
// Fused index scores + top-K membership, v7 (R11): 8 rows/block, 512 threads,
// 256 blocks (1/CU). Rationale: per-block kI staging cost is independent of
// row count, so total staging scales as S/rows_per_block -- R6 showed 2 rows
// = 66us, R0 4 rows = 41us; 8 rows halves total staging vs R0. Per-wave
// compute mapping is R0-exact (wave = 1 row, lane = key); skeys/shist are
// per-wave -> barrier-free radix preserved verbatim. LDS 64.8 KB.
// ---------------------------------------------------------------------------
__global__ __launch_bounds__(512) void score_topk_kernel(
    const float* __restrict__ qIk,
    const int* __restrict__ coords, const float* __restrict__ rpe_table,
    const float* __restrict__ W1g, const float* __restrict__ b1g,
    const float* __restrict__ W2g, const float* __restrict__ b2g,
    unsigned* __restrict__ selmask)
{
    __shared__ float skI[64][132];
    __shared__ float sqI2[8][IDH2_];
    __shared__ unsigned skeys[8][LI_];
    __shared__ int shist[8][256];
    __shared__ float srpe[NBUCK_ * IH_];
    __shared__ float sW1[GH_ * IH_], sb1[GH_], sW2[IH_ * GH_], sb2[IH_];

    int tid  = threadIdx.x;
    int lane = tid & 63;
    int wv   = tid >> 6;                  // 0..7
    int row  = blockIdx.x * 8 + wv;
    int n    = (blockIdx.x * 8) >> 9;

    for (int i = tid; i < NBUCK_ * IH_; i += 512) srpe[i] = rpe_table[i];
    if (tid < 32) sW1[tid] = W1g[tid];
    else if (tid < 64) sW2[tid - 32] = W2g[tid - 32];
    else if (tid < 72) sb1[tid - 64] = b1g[tid - 64];
    else if (tid < 76) sb2[tid - 72] = b2g[tid - 72];
    for (int i = tid; i < 8 * IDH2_; i += 512)
        sqI2[i >> 7][i & 127] =
            qIk[(size_t)(blockIdx.x * 8 + (i >> 7)) * 256 + (i & 127)];
    int pq = coords[row * 2 + 1];

    for (int kt = 0; kt < 8; kt++) {
        __syncthreads();
        {
            // 64 rows x 32 float4 chunks = 2048 chunks, 512 threads x 4
#pragma unroll
            for (int j = 0; j < 4; j++) {
                int f = j * 512 + tid;
                int key = f >> 5, c = f & 31;
                const float* src = qIk +
                    (size_t)(n * LI_ + kt * 64 + key) * 256 + 128 + 4 * c;
                *(float4*)&skI[key][4 * c] = *(const float4*)src;
            }
        }
        __syncthreads();

        int kloc = lane;
        int kg   = kt * 64 + kloc;
        const float* sq = &sqI2[wv][0];
        float dh[8];
#pragma unroll
        for (int hh = 0; hh < 8; hh++) {
            float acc = 0.0f;
#pragma unroll
            for (int d = 0; d < 16; d += 4) {
                float4 kv = *(const float4*)&skI[kloc][hh * 16 + d];
                acc += sq[hh * 16 + d + 0] * kv.x + sq[hh * 16 + d + 1] * kv.y +
                       sq[hh * 16 + d + 2] * kv.z + sq[hh * 16 + d + 3] * kv.w;
            }
            dh[hh] = acc;
        }
        int pk = coords[(n * LI_ + kg) * 2 + 1];
        int rel = pq - pk;
        rel = rel < -MAXREL_ ? -MAXREL_ : (rel > MAXREL_ ? MAXREL_ : rel);
        const float* rp = srpe + (rel + MAXREL_) * IH_;
        float t1[GH_];
#pragma unroll
        for (int g = 0; g < GH_; g++) t1[g] = sb1[g];
#pragma unroll
        for (int j = 0; j < IH_; j++) {
            float gate = dh[IH_ + j] + rp[j];
#pragma unroll
            for (int g = 0; g < GH_; g++) t1[g] += gate * sW1[g * IH_ + j];
        }
#pragma unroll
        for (int g = 0; g < GH_; g++) t1[g] = fmaxf(t1[g], 0.0f);
        float score = 0.0f;
#pragma unroll
        for (int j = 0; j < IH_; j++) {
            float t2 = sb2[j];
#pragma unroll
            for (int g = 0; g < GH_; g++) t2 += t1[g] * sW2[j * GH_ + g];
            float sg = 1.0f / (1.0f + expf(-t2));
            float rs = fmaxf(dh[j] + rp[j], 0.0f);
            score += rs * sg;
        }
        unsigned bits = __float_as_uint(score);
        skeys[wv][kg] = (bits & 0x80000000u) ? ~bits : (bits | 0x80000000u);
    }
    // no barrier: skeys[wv]/shist[wv] per-wave; same-wave DS ops in-order

    unsigned pref = 0u;
    int kcur = K_;
    const unsigned himask[4] = {0u, 0xFF000000u, 0xFFFF0000u, 0xFFFFFF00u};
#pragma unroll
    for (int pass = 0; pass < 4; pass++) {
        int shift = 24 - pass * 8;
        unsigned hm = himask[pass];
        *(int4*)&shist[wv][4 * lane] = make_int4(0, 0, 0, 0);
#pragma unroll
        for (int c = 0; c < 8; c++) {
            unsigned key = skeys[wv][c * 64 + lane];
            if ((key & hm) == pref) atomicAdd(&shist[wv][(key >> shift) & 255], 1);
        }
        int4 b4 = *(const int4*)&shist[wv][4 * lane];
        int b[4] = {b4.x, b4.y, b4.z, b4.w};
        int t = b[0] + b[1] + b[2] + b[3];
        int Ssum = t;
#pragma unroll
        for (int off = 1; off < 64; off <<= 1) {
            int u = __shfl_down(Ssum, off, 64);
            if (lane + off < 64) Ssum += u;
        }
        int E = Ssum - t;
        int cs[5];
        cs[4] = E;
        cs[3] = b[3] + E;
        cs[2] = b[2] + cs[3];
        cs[1] = b[1] + cs[2];
        cs[0] = b[0] + cs[1];
        bool found = false;
        unsigned cpref = 0u; int ck = 0;
#pragma unroll
        for (int j = 0; j < 4; j++) {
            if (!found && cs[j] >= kcur && cs[j + 1] < kcur) {
                found = true;
                cpref = pref | ((unsigned)(4 * lane + j) << shift);
                ck = kcur - cs[j + 1];
            }
        }
        unsigned long long bm = __ballot(found);
        int src = __ffsll((long long)bm) - 1;
        pref = (unsigned)__shfl((int)cpref, src, 64);
        kcur = __shfl(ck, src, 64);
    }
    unsigned Tu = pref;

    unsigned long long bg[8], be[8];
#pragma unroll
    for (int c = 0; c < 8; c++) {
        unsigned key = skeys[wv][c * 64 + lane];
        bg[c] = __ballot(key > Tu);
        be[c] = __ballot(key == Tu);
    }
    if (lane < 16) {
        int total_gt = 0;
#pragma unroll
        for (int c = 0; c < 8; c++) total_gt += __popcll(bg[c]);
        int base = 0;
#pragma unroll
        for (int c = 0; c < 8; c++) {
            if (2 * c < lane)     base += __popc((unsigned)be[c]);
            if (2 * c + 1 < lane) base += __popc((unsigned)(be[c] >> 32));
        }
        unsigned gw = (unsigned)(bg[lane >> 1] >> (32 * (lane & 1)));
        unsigned ew = (unsigned)(be[lane >> 1] >> (32 * (lane & 1)));
        int ne = K_ - total_gt - base;
        int pc = __popc(ew);
        int m = ne < 0 ? 0 : (ne > pc ? pc : ne);
        while (pc > m) { ew ^= (1u << (31 - __clz(ew))); pc--; }
        selmask[(size_t)row * 16 + lane] = gw | ew;
    }
}

// ---------------------------------------------------------------------------
// Dense-masked attention v7 (R7-exact): T14 async-STAGE prefetch, Q frags
// hoisted, setprio around MFMA clusters, separate P buffer, 2 barriers/kt.
// ---------------------------------------------------------------------------
__global__ __launch_bounds__(256) void attn_kernel(
    const unsigned short* __restrict__ qkvh, const unsigned short* __restrict__ qkvl,
    const unsigned* __restrict__ selmask,
    unsigned short* __restrict__ outh, unsigned short* __restrict__ outl)
{
    __shared__ unsigned short Qh[64 * 72],  Ql[64 * 72];   // [q][d]
    __shared__ unsigned short Kh[64 * 72],  Kl[64 * 72];   // [key][d]
    __shared__ unsigned short VTh[64 * 72], VTl[64 * 72];  // V^T [d][key]
    __shared__ unsigned short Ph[64 * 72],  Pl[64 * 72];   // P [q][key]
    __shared__ unsigned Ms[64][16];

    int b  = blockIdx.x;
    int qt = b >> 6;                 // XCD swizzle: qt in high bits
    int nh = b & 63;
    int h  = nh & 15;
    int n  = nh >> 4;
    int tid = threadIdx.x;
    int lane = tid & 63, w = tid >> 6;
    int lane15 = lane & 15, quad = lane >> 4;
    int q0 = n * LI_ + qt * 64;

    for (int i = tid; i < 64 * 16; i += 256)
        Ms[i >> 4][i & 15] = selmask[(size_t)(q0 + (i >> 4)) * 16 + (i & 15)];

    // stage Q once (already rope'd, scaled, split)
    {
        int r = tid >> 2, c0 = (tid & 3) * 16;
        size_t off = (size_t)(q0 + r) * 3072 + h * 64 + c0;
        *(uint4*)&Qh[r * 72 + c0]     = *(const uint4*)(qkvh + off);
        *(uint4*)&Qh[r * 72 + c0 + 8] = *(const uint4*)(qkvh + off + 8);
        *(uint4*)&Ql[r * 72 + c0]     = *(const uint4*)(qkvl + off);
        *(uint4*)&Ql[r * 72 + c0 + 8] = *(const uint4*)(qkvl + off + 8);
    }
    __syncthreads();   // Q staged -> hoist fragments to registers once
    bf16x8 qfh[2], qfl[2];
#pragma unroll
    for (int ks = 0; ks < 2; ks++) {
        qfh[ks] = *(const bf16x8*)&Qh[(16 * w + lane15) * 72 + ks * 32 + quad * 8];
        qfl[ks] = *(const bf16x8*)&Ql[(16 * w + lane15) * 72 + ks * 32 + quad * 8];
    }

    // prefetch addressing (constant per thread)
    int kr = tid >> 2, kc0 = (tid & 3) * 16;          // K stage coords
    int vd = lane, vk0 = w * 16;                      // V stage coords
    const size_t kbase = (size_t)n * LI_ * 3072 + 1024 + h * 64;
    const size_t vbase = (size_t)n * LI_ * 3072 + 2048 + h * 64;

    uint4 pkh0, pkh1, pkl0, pkl1;                     // K prefetch regs
    unsigned short pvh[16], pvl[16];                  // V prefetch regs

#define LOADT(KT)                                                              \
    {                                                                          \
        size_t offK = kbase + (size_t)((KT) * 64 + kr) * 3072 + kc0;           \
        pkh0 = *(const uint4*)(qkvh + offK);                                   \
        pkh1 = *(const uint4*)(qkvh + offK + 8);                               \
        pkl0 = *(const uint4*)(qkvl + offK);                                   \
        pkl1 = *(const uint4*)(qkvl + offK + 8);                               \
        size_t offV = vbase + (size_t)((KT) * 64 + vk0) * 3072 + vd;           \
        _Pragma("unroll")                                                      \
        for (int j = 0; j < 16; j++) {                                         \
            pvh[j] = qkvh[offV + (size_t)j * 3072];                            \
            pvl[j] = qkvl[offV + (size_t)j * 3072];                            \
        }                                                                      \
    }

    LOADT(0);

    f32x4 o_acc[4];
#pragma unroll
    for (int i = 0; i < 4; i++) o_acc[i] = (f32x4){0.f, 0.f, 0.f, 0.f};
    float rsum[4] = {};

    for (int kt = 0; kt < 8; kt++) {
        __syncthreads();   // prev iter's Kh (QK) and VTh (PV) reads done
        // reg -> LDS writes only (loads were issued last iteration)
        *(uint4*)&Kh[kr * 72 + kc0]      = pkh0;
        *(uint4*)&Kh[kr * 72 + kc0 + 8]  = pkh1;
        *(uint4*)&Kl[kr * 72 + kc0]      = pkl0;
        *(uint4*)&Kl[kr * 72 + kc0 + 8]  = pkl1;
        *(uint4*)&VTh[vd * 72 + vk0]     = *(uint4*)&pvh[0];
        *(uint4*)&VTh[vd * 72 + vk0 + 8] = *(uint4*)&pvh[8];
        *(uint4*)&VTl[vd * 72 + vk0]     = *(uint4*)&pvl[0];
        *(uint4*)&VTl[vd * 72 + vk0 + 8] = *(uint4*)&pvl[8];
        __syncthreads();   // stage visible to all waves

        // issue next tile's loads; latency hides under QK/softmax/PV
        if (kt < 7) LOADT(kt + 1);

        // QK: wave w computes q-tile w vs all 4 key-tiles, bf16x3
        f32x4 s_acc[4];
#pragma unroll
        for (int nt = 0; nt < 4; nt++) s_acc[nt] = (f32x4){0.f, 0.f, 0.f, 0.f};
        __builtin_amdgcn_s_setprio(1);
#pragma unroll
        for (int nt = 0; nt < 4; nt++) {
#pragma unroll
            for (int ks = 0; ks < 2; ks++) {
                bf16x8 kfh = *(const bf16x8*)&Kh[(16 * nt + lane15) * 72 + ks * 32 + quad * 8];
                bf16x8 kfl = *(const bf16x8*)&Kl[(16 * nt + lane15) * 72 + ks * 32 + quad * 8];
                s_acc[nt] = __builtin_amdgcn_mfma_f32_16x16x32_bf16(qfh[ks], kfh, s_acc[nt], 0, 0, 0);
                s_acc[nt] = __builtin_amdgcn_mfma_f32_16x16x32_bf16(qfh[ks], kfl, s_acc[nt], 0, 0, 0);
                s_acc[nt] = __builtin_amdgcn_mfma_f32_16x16x32_bf16(qfl[ks], kfh, s_acc[nt], 0, 0, 0);
            }
        }
        __builtin_amdgcn_s_setprio(0);

        // softmax + P split; writes only this wave's P rows -> no barrier
#pragma unroll
        for (int nt = 0; nt < 4; nt++) {
            int kb = kt * 64 + nt * 16 + lane15;
            int wi = kb >> 5, bit = kb & 31;
#pragma unroll
            for (int reg = 0; reg < 4; reg++) {
                int qloc = 16 * w + quad * 4 + reg;
                unsigned mw = Ms[qloc][wi];
                float p = ((mw >> bit) & 1u) ? __expf(s_acc[nt][reg]) : 0.0f;
                rsum[reg] += p;
                unsigned short ph = f2bf(p);
                Ph[qloc * 72 + nt * 16 + lane15] = ph;
                Pl[qloc * 72 + nt * 16 + lane15] = f2bf(p - bf2f(ph));
            }
        }

        // PV: A = P [q][key] (own rows), B = V^T [d][key], bf16x3
        {
            bf16x8 pfh[2], pfl[2];
#pragma unroll
            for (int ks = 0; ks < 2; ks++) {
                pfh[ks] = *(const bf16x8*)&Ph[(16 * w + lane15) * 72 + ks * 32 + quad * 8];
                pfl[ks] = *(const bf16x8*)&Pl[(16 * w + lane15) * 72 + ks * 32 + quad * 8];
            }
            __builtin_amdgcn_s_setprio(1);
#pragma unroll
            for (int dt = 0; dt < 4; dt++) {
#pragma unroll
                for (int ks = 0; ks < 2; ks++) {
                    bf16x8 vfh = *(const bf16x8*)&VTh[(16 * dt + lane15) * 72 + ks * 32 + quad * 8];
                    bf16x8 vfl = *(const bf16x8*)&VTl[(16 * dt + lane15) * 72 + ks * 32 + quad * 8];
                    o_acc[dt] = __builtin_amdgcn_mfma_f32_16x16x32_bf16(pfh[ks], vfh, o_acc[dt], 0, 0, 0);
                    o_acc[dt] = __builtin_amdgcn_mfma_f32_16x16x32_bf16(pfh[ks], vfl, o_acc[dt], 0, 0, 0);
                    o_acc[dt] = __builtin_amdgcn_mfma_f32_16x16x32_bf16(pfl[ks], vfh, o_acc[dt], 0, 0, 0);
                }
            }
            __builtin_amdgcn_s_setprio(0);
        }
    }
#undef LOADT

    // row sums: reduce over the 16 lanes (lane15) sharing each q row
#pragma unroll
    for (int reg = 0; reg < 4; reg++) {
        rsum[reg] += __shfl_xor(rsum[reg], 1, 64);
        rsum[reg] += __shfl_xor(rsum[reg], 2, 64);
        rsum[reg] += __shfl_xor(rsum[reg], 4, 64);
        rsum[reg] += __shfl_xor(rsum[reg], 8, 64);
    }

    // epilogue: normalize, split hi/lo, store
#pragma unroll
    for (int dt = 0; dt < 4; dt++) {
#pragma unroll
        for (int reg = 0; reg < 4; reg++) {
            float v = o_acc[dt][reg] / rsum[reg];
            size_t ob = (size_t)(q0 + 16 * w + quad * 4 + reg) * 1024 + h * 64 + 16 * dt + lane15;
            unsigned short hh = f2bf(v);
            outh[ob] = hh;
            outl[ob] = f2bf(v - bf2f(hh));
        }
    }
}

// ---------------------------------------------------------------------------
extern "C" void kernel_launch(void* const* d_in, const int* in_sizes, int n_in,
                              void* d_out, int out_size, void* d_ws, size_t ws_size,
                              hipStream_t stream)
{
    const float* hidden  = (const float*)d_in[0];
    const int*   coords  = (const int*)d_in[1];
    const float* rope    = (const float*)d_in[3];
    const float* Wq_idx  = (const float*)d_in[4];
    const float* Wk_idx  = (const float*)d_in[5];
    const float* W1g     = (const float*)d_in[6];
    const float* b1g     = (const float*)d_in[7];
    const float* W2g     = (const float*)d_in[8];
    const float* b2g     = (const float*)d_in[9];
    const float* rpe     = (const float*)d_in[10];
    const float* Wqkv_d  = (const float*)d_in[11];
    const float* bqkv_d  = (const float*)d_in[12];
    const float* Wqkv_u  = (const float*)d_in[13];
    const float* bqkv_u  = (const float*)d_in[14];
    const float* Wp_d    = (const float*)d_in[15];
    const float* bp_d    = (const float*)d_in[16];
    const float* Wp_u    = (const float*)d_in[17];
    const float* bp_u    = (const float*)d_in[18];
    const float* scaler  = (const float*)d_in[19];
    float* out = (float*)d_out;

    unsigned short* sp_hi  = (unsigned short*)d_ws;
    unsigned short* sp_lo  = sp_hi + NSPLIT_;
    unsigned short* mid_hi = sp_lo + NSPLIT_;
    unsigned short* mid_lo = mid_hi + (size_t)S_ * BOT_;
    float* qkv = (float*)(mid_lo + (size_t)S_ * BOT_);   // slot kept (unused)
    float* qIk = qkv + (size_t)S_ * 3 * DIM_;
    unsigned* selmask = (unsigned*)(qIk + (size_t)S_ * 256);
    unsigned short* qkvh = (unsigned short*)(selmask + (size_t)S_ * 16);
    unsigned short* qkvl = qkvh + (size_t)S_ * 3 * DIM_;
    float* cost = (float*)(qkvl + (size_t)S_ * 3 * DIM_);
    float* sint = cost + NTRIG_;

    // 0) split hidden + all weights into hi/lo bf16, precompute cos/sin
    split_all_kernel<<<((NSPLIT_ + NTRIG_) / 4 + 255) / 256, 256, 0, stream>>>(
        hidden, Wqkv_d, Wq_idx, Wk_idx, Wqkv_u, Wp_d, Wp_u, rope,
        sp_hi, sp_lo, cost, sint);

    // 1) fused gemm1: hidden @ [Wqkv_d;Wq;Wk]^T -> mid(hi/lo) + qIk(fp32)
    gemm64_bf16x3<<<dim3(512 / 64, S_ / 64), 256, 0, stream>>>(
        sp_hi, sp_lo, sp_hi + OFF_W1_, sp_lo + OFF_W1_,
        bqkv_d, nullptr, qIk, mid_hi, mid_lo, S_, 512, DIM_, 256);

    // 2) fused index scores + top-k membership (8 rows/block, 256 blocks)
    score_topk_kernel<<<S_ / 8, 512, 0, stream>>>(
        qIk, coords, rpe, W1g, b1g, W2g, b2g, selmask);

    // 3) qkv = mid @ Wqkv_u^T + b, fused RoPE (table cos/sin) + hi/lo split
    gemm_qkv_rope<<<dim3(3 * DIM_ / 64, S_ / 128), 256, 0, stream>>>(
        mid_hi, mid_lo, sp_hi + OFF_WQKVU_, sp_lo + OFF_WQKVU_,
        bqkv_u, cost, sint, qkvh, qkvl);

    // 4) MFMA attention (T14 prefetch; emits attout hi/lo into split slots)
    attn_kernel<<<NIMG_ * H_ * 8, 256, 0, stream>>>(qkvh, qkvl, selmask, sp_hi, sp_lo);

    // 5) mid2 = attout @ Wp_d^T + b (hi/lo)
    gemm64_bf16x3<<<dim3(BOT_ / 64, S_ / 64), 256, 0, stream>>>(
        sp_hi, sp_lo, sp_hi + OFF_WPD_, sp_lo + OFF_WPD_,
        bp_d, nullptr, nullptr, mid_hi, mid_lo, S_, BOT_, DIM_, BOT_);

    // 6) out = mid2 @ Wp_u^T + b, *scaler (fp32)
    gemm_bf16x3<<<dim3(DIM_ / 64, S_ / 128), 256, 0, stream>>>(
        mid_hi, mid_lo, sp_hi + OFF_WPU_, sp_lo + OFF_WPU_,
        bp_u, scaler, out, S_, DIM_, BOT_);
}

// Round 12
// 237.392 us; speedup vs baseline: 1.1080x; 1.0364x over previous
//
#include <hip/hip_runtime.h>
#include <hip/hip_bf16.h>

// Problem constants
#define S_    2048
#define DIM_  1024
#define H_    16
#define DH_   64
#define BOT_  256
#define NIMG_ 4
#define LI_   512
#define K_    256
#define IH_   4
#define ID_   16
#define MAXREL_ 64
#define NBUCK_ 129
#define GH_   8
#define IDH2_ 128   // 2*IH*ID

typedef short bf16x8 __attribute__((ext_vector_type(8)));
typedef float f32x4  __attribute__((ext_vector_type(4)));

__device__ __forceinline__ unsigned short f2bf(float x) {   // RNE float->bf16
    unsigned u = __float_as_uint(x);
    return (unsigned short)((u + 0x7fffu + ((u >> 16) & 1u)) >> 16);
}
__device__ __forceinline__ float bf2f(unsigned short h) {
    return __uint_as_float(((unsigned)h) << 16);
}

// Split-region element offsets (ushort units). W1 = [Wqkv_d;Wq;Wk] contiguous.
#define OFF_W1_    2097152
#define OFF_WQ_    2359296
#define OFF_WK_    2490368
#define OFF_WQKVU_ 2621440
#define OFF_WPD_   3407872
#define OFF_WPU_   3670016
#define NSPLIT_    3932160
#define NTRIG_     65536      // S_*32 cos/sin table entries

// ---------------------------------------------------------------------------
// Fused hi/lo bf16 split of hidden + all 6 weight matrices + cos/sin tables.
// ---------------------------------------------------------------------------
__global__ __launch_bounds__(256) void split_all_kernel(
    const float* __restrict__ hid, const float* __restrict__ wqd,
    const float* __restrict__ wq,  const float* __restrict__ wk,
    const float* __restrict__ wqu, const float* __restrict__ wpd,
    const float* __restrict__ wpu, const float* __restrict__ rope,
    unsigned short* __restrict__ hi, unsigned short* __restrict__ lo,
    float* __restrict__ cost, float* __restrict__ sint)
{
    long e = ((long)blockIdx.x * 256 + threadIdx.x) * 4;
    if (e >= NSPLIT_ + NTRIG_) return;
    if (e >= NSPLIT_) {                      // trig-table segment
        long t = e - NSPLIT_;
        float4 r = *(const float4*)(rope + t);
        float4 c, s;
        c.x = cosf(r.x); s.x = sinf(r.x);
        c.y = cosf(r.y); s.y = sinf(r.y);
        c.z = cosf(r.z); s.z = sinf(r.z);
        c.w = cosf(r.w); s.w = sinf(r.w);
        *(float4*)&cost[t] = c;
        *(float4*)&sint[t] = s;
        return;
    }
    const float* src; long off;
    if (e < OFF_W1_)         { src = hid; off = 0; }
    else if (e < OFF_WQ_)    { src = wqd; off = OFF_W1_; }
    else if (e < OFF_WK_)    { src = wq;  off = OFF_WQ_; }
    else if (e < OFF_WQKVU_) { src = wk;  off = OFF_WK_; }
    else if (e < OFF_WPD_)   { src = wqu; off = OFF_WQKVU_; }
    else if (e < OFF_WPU_)   { src = wpd; off = OFF_WPD_; }
    else                     { src = wpu; off = OFF_WPU_; }
    float4 v = *(const float4*)(src + (e - off));
    ushort4 h, l;
    h.x = f2bf(v.x); l.x = f2bf(v.x - bf2f(h.x));
    h.y = f2bf(v.y); l.y = f2bf(v.y - bf2f(h.y));
    h.z = f2bf(v.z); l.z = f2bf(v.z - bf2f(h.z));
    h.w = f2bf(v.w); l.w = f2bf(v.w - bf2f(h.w));
    *(ushort4*)&hi[e] = h;
    *(ushort4*)&lo[e] = l;
}

// ---------------------------------------------------------------------------
// bf16x3 MFMA GEMM, 128x64 tile (large-N: p_u). R12: T14 prefetch -- next
// K-tile's global loads issued into registers during current MFMA phase
// (R7-proven on attn; these GEMMs run at <=1-3 blocks/CU so staging latency
// was exposed between the per-iter barriers).
// ---------------------------------------------------------------------------
__global__ __launch_bounds__(256) void gemm_bf16x3(
    const unsigned short* __restrict__ Ah, const unsigned short* __restrict__ Al,
    const unsigned short* __restrict__ Bh, const unsigned short* __restrict__ Bl,
    const float* __restrict__ bias, const float* __restrict__ scale_ptr,
    float* __restrict__ Cf, int M, int N, int Kd)
{
    __shared__ unsigned short sAh[128 * 40], sAl[128 * 40];
    __shared__ unsigned short sBh[64 * 40],  sBl[64 * 40];
    int tid = threadIdx.x;
    int lane = tid & 63, wv = tid >> 6;
    int wr = wv >> 1, wc = wv & 1;
    int row0 = blockIdx.y * 128, col0 = blockIdx.x * 64;

    f32x4 acc[4][2];
#pragma unroll
    for (int i = 0; i < 4; i++)
#pragma unroll
        for (int j = 0; j < 2; j++) acc[i][j] = (f32x4){0.f, 0.f, 0.f, 0.f};

    int ar = tid >> 1, ac = (tid & 1) * 16;
    int br = tid >> 2, bc = (tid & 3) * 8;
    const unsigned short* gAh = Ah + (size_t)(row0 + ar) * Kd + ac;
    const unsigned short* gAl = Al + (size_t)(row0 + ar) * Kd + ac;
    const unsigned short* gBh = Bh + (size_t)(col0 + br) * Kd + bc;
    const unsigned short* gBl = Bl + (size_t)(col0 + br) * Kd + bc;
    int am = lane & 15, qk = (lane >> 4) * 8;

    float4 pA0, pA1, pA2, pA3, pB0, pB1;
#define G128_LOAD(K0)                                      \
    {                                                      \
        pA0 = *(const float4*)(gAh + (K0));                \
        pA1 = *(const float4*)(gAh + (K0) + 8);            \
        pA2 = *(const float4*)(gAl + (K0));                \
        pA3 = *(const float4*)(gAl + (K0) + 8);            \
        pB0 = *(const float4*)(gBh + (K0));                \
        pB1 = *(const float4*)(gBl + (K0));                \
    }
    G128_LOAD(0);

    for (int k0 = 0; k0 < Kd; k0 += 32) {
        __syncthreads();
        *(float4*)&sAh[ar * 40 + ac]     = pA0;
        *(float4*)&sAh[ar * 40 + ac + 8] = pA1;
        *(float4*)&sAl[ar * 40 + ac]     = pA2;
        *(float4*)&sAl[ar * 40 + ac + 8] = pA3;
        *(float4*)&sBh[br * 40 + bc]     = pB0;
        *(float4*)&sBl[br * 40 + bc]     = pB1;
        __syncthreads();
        if (k0 + 32 < Kd) G128_LOAD(k0 + 32);

        bf16x8 ah[4], al[4], bh[2], bl[2];
#pragma unroll
        for (int rt = 0; rt < 4; rt++) {
            int r = wr * 64 + rt * 16 + am;
            ah[rt] = *(const bf16x8*)&sAh[r * 40 + qk];
            al[rt] = *(const bf16x8*)&sAl[r * 40 + qk];
        }
#pragma unroll
        for (int ct = 0; ct < 2; ct++) {
            int c = wc * 32 + ct * 16 + am;
            bh[ct] = *(const bf16x8*)&sBh[c * 40 + qk];
            bl[ct] = *(const bf16x8*)&sBl[c * 40 + qk];
        }
#pragma unroll
        for (int rt = 0; rt < 4; rt++)
#pragma unroll
            for (int ct = 0; ct < 2; ct++) {
                acc[rt][ct] = __builtin_amdgcn_mfma_f32_16x16x32_bf16(ah[rt], bh[ct], acc[rt][ct], 0, 0, 0);
                acc[rt][ct] = __builtin_amdgcn_mfma_f32_16x16x32_bf16(ah[rt], bl[ct], acc[rt][ct], 0, 0, 0);
                acc[rt][ct] = __builtin_amdgcn_mfma_f32_16x16x32_bf16(al[rt], bh[ct], acc[rt][ct], 0, 0, 0);
            }
    }
#undef G128_LOAD

    float scl = scale_ptr ? *scale_ptr : 1.0f;
    int rq = (lane >> 4) * 4;
#pragma unroll
    for (int rt = 0; rt < 4; rt++)
#pragma unroll
        for (int ct = 0; ct < 2; ct++) {
            int col = col0 + wc * 32 + ct * 16 + am;
            float bz = bias ? bias[col] : 0.0f;
#pragma unroll
            for (int rg = 0; rg < 4; rg++) {
                int row = row0 + wr * 64 + rt * 16 + rq + rg;
                Cf[(size_t)row * N + col] = (acc[rt][ct][rg] + bz) * scl;
            }
        }
}

// ---------------------------------------------------------------------------
// gemm_qkv_rope: fused gemm2 + RoPE (table cos/sin) + hi/lo split, with T14
// prefetch (R12).
// ---------------------------------------------------------------------------
__global__ __launch_bounds__(256) void gemm_qkv_rope(
    const unsigned short* __restrict__ Ah, const unsigned short* __restrict__ Al,
    const unsigned short* __restrict__ Bh, const unsigned short* __restrict__ Bl,
    const float* __restrict__ bias, const float* __restrict__ cost,
    const float* __restrict__ sint,
    unsigned short* __restrict__ qkvh, unsigned short* __restrict__ qkvl)
{
    __shared__ unsigned short sAh[128 * 40], sAl[128 * 40];
    __shared__ unsigned short sBh[64 * 40],  sBl[64 * 40];
    int tid = threadIdx.x;
    int lane = tid & 63, wv = tid >> 6;
    int wr = wv >> 1, wc = wv & 1;
    int row0 = blockIdx.y * 128, col0 = blockIdx.x * 64;
    const int Kd = BOT_;

    f32x4 acc[4][2];
#pragma unroll
    for (int i = 0; i < 4; i++)
#pragma unroll
        for (int j = 0; j < 2; j++) acc[i][j] = (f32x4){0.f, 0.f, 0.f, 0.f};

    int ar = tid >> 1, ac = (tid & 1) * 16;
    int br = tid >> 2, bc = (tid & 3) * 8;
    const unsigned short* gAh = Ah + (size_t)(row0 + ar) * Kd + ac;
    const unsigned short* gAl = Al + (size_t)(row0 + ar) * Kd + ac;
    const unsigned short* gBh = Bh + (size_t)(col0 + br) * Kd + bc;
    const unsigned short* gBl = Bl + (size_t)(col0 + br) * Kd + bc;
    int am = lane & 15, qk = (lane >> 4) * 8;

    float4 pA0, pA1, pA2, pA3, pB0, pB1;
#define GQR_LOAD(K0)                                       \
    {                                                      \
        pA0 = *(const float4*)(gAh + (K0));                \
        pA1 = *(const float4*)(gAh + (K0) + 8);            \
        pA2 = *(const float4*)(gAl + (K0));                \
        pA3 = *(const float4*)(gAl + (K0) + 8);            \
        pB0 = *(const float4*)(gBh + (K0));                \
        pB1 = *(const float4*)(gBl + (K0));                \
    }
    GQR_LOAD(0);

    for (int k0 = 0; k0 < Kd; k0 += 32) {
        __syncthreads();
        *(float4*)&sAh[ar * 40 + ac]     = pA0;
        *(float4*)&sAh[ar * 40 + ac + 8] = pA1;
        *(float4*)&sAl[ar * 40 + ac]     = pA2;
        *(float4*)&sAl[ar * 40 + ac + 8] = pA3;
        *(float4*)&sBh[br * 40 + bc]     = pB0;
        *(float4*)&sBl[br * 40 + bc]     = pB1;
        __syncthreads();
        if (k0 + 32 < Kd) GQR_LOAD(k0 + 32);

        bf16x8 ah[4], al[4], bh[2], bl[2];
#pragma unroll
        for (int rt = 0; rt < 4; rt++) {
            int r = wr * 64 + rt * 16 + am;
            ah[rt] = *(const bf16x8*)&sAh[r * 40 + qk];
            al[rt] = *(const bf16x8*)&sAl[r * 40 + qk];
        }
#pragma unroll
        for (int ct = 0; ct < 2; ct++) {
            int c = ct * 32 + wc * 16 + am;      // remapped: rope pair in-reg
            bh[ct] = *(const bf16x8*)&sBh[c * 40 + qk];
            bl[ct] = *(const bf16x8*)&sBl[c * 40 + qk];
        }
#pragma unroll
        for (int rt = 0; rt < 4; rt++)
#pragma unroll
            for (int ct = 0; ct < 2; ct++) {
                acc[rt][ct] = __builtin_amdgcn_mfma_f32_16x16x32_bf16(ah[rt], bh[ct], acc[rt][ct], 0, 0, 0);
                acc[rt][ct] = __builtin_amdgcn_mfma_f32_16x16x32_bf16(ah[rt], bl[ct], acc[rt][ct], 0, 0, 0);
                acc[rt][ct] = __builtin_amdgcn_mfma_f32_16x16x32_bf16(al[rt], bh[ct], acc[rt][ct], 0, 0, 0);
            }
    }
#undef GQR_LOAD

    int sec  = blockIdx.x >> 4;        // 0=q, 1=k, 2=v
    int hd   = blockIdx.x & 15;
    int d_lo = wc * 16 + am;           // 0..31
    float b1 = bias[col0 + d_lo];
    float b2 = bias[col0 + 32 + d_lo];
    int rq = (lane >> 4) * 4;
#pragma unroll
    for (int rt = 0; rt < 4; rt++)
#pragma unroll
        for (int rg = 0; rg < 4; rg++) {
            int row = row0 + wr * 64 + rt * 16 + rq + rg;
            float x1 = acc[rt][0][rg] + b1;
            float x2 = acc[rt][1][rg] + b2;
            float o1, o2;
            if (sec < 2) {
                float cs = cost[row * 32 + d_lo];
                float sn = sint[row * 32 + d_lo];
                o1 = x1 * cs - x2 * sn;
                o2 = x2 * cs + x1 * sn;
                if (sec == 0) { o1 *= 0.125f; o2 *= 0.125f; }
            } else {
                o1 = x1; o2 = x2;
            }
            size_t base = (size_t)row * 3072 + sec * 1024 + hd * 64 + d_lo;
            unsigned short h1 = f2bf(o1);
            qkvh[base] = h1;       qkvl[base] = f2bf(o1 - bf2f(h1));
            unsigned short h2 = f2bf(o2);
            qkvh[base + 32] = h2;  qkvl[base + 32] = f2bf(o2 - bf2f(h2));
        }
}

// ---------------------------------------------------------------------------
// bf16x3 MFMA GEMM, 64x64 tile, BK=64 (gemm1, p_d), with T14 prefetch (R12).
// gemm1 runs at 1 block/CU and p_d at 0.5 blocks/CU -- no TLP to hide the
// staging latency, so register prefetch across the MFMA phase is the lever.
// ---------------------------------------------------------------------------
__global__ __launch_bounds__(256) void gemm64_bf16x3(
    const unsigned short* __restrict__ Ah, const unsigned short* __restrict__ Al,
    const unsigned short* __restrict__ Bh, const unsigned short* __restrict__ Bl,
    const float* __restrict__ bias_lo, const float* __restrict__ bias_hi,
    float* __restrict__ Cf, unsigned short* __restrict__ Chi,
    unsigned short* __restrict__ Clo, int M, int N, int Kd, int split_col)
{
    __shared__ unsigned short sAh[64 * 72], sAl[64 * 72];
    __shared__ unsigned short sBh[64 * 72], sBl[64 * 72];
    int tid = threadIdx.x;
    int lane = tid & 63, wv = tid >> 6;
    int wr = wv >> 1, wc = wv & 1;          // wave 32x32
    int row0 = blockIdx.y * 64, col0 = blockIdx.x * 64;

    f32x4 acc[2][2];
#pragma unroll
    for (int i = 0; i < 2; i++)
#pragma unroll
        for (int j = 0; j < 2; j++) acc[i][j] = (f32x4){0.f, 0.f, 0.f, 0.f};

    int sr = tid >> 2, sc = (tid & 3) * 16;   // row, 16-elem chunk of 64
    const unsigned short* gAh = Ah + (size_t)(row0 + sr) * Kd + sc;
    const unsigned short* gAl = Al + (size_t)(row0 + sr) * Kd + sc;
    const unsigned short* gBh = Bh + (size_t)(col0 + sr) * Kd + sc;
    const unsigned short* gBl = Bl + (size_t)(col0 + sr) * Kd + sc;
    int am = lane & 15, qk = (lane >> 4) * 8;

    float4 pA0, pA1, pA2, pA3, pB0, pB1, pB2, pB3;
#define G64_LOAD(K0)                                       \
    {                                                      \
        pA0 = *(const float4*)(gAh + (K0));                \
        pA1 = *(const float4*)(gAh + (K0) + 8);            \
        pA2 = *(const float4*)(gAl + (K0));                \
        pA3 = *(const float4*)(gAl + (K0) + 8);            \
        pB0 = *(const float4*)(gBh + (K0));                \
        pB1 = *(const float4*)(gBh + (K0) + 8);            \
        pB2 = *(const float4*)(gBl + (K0));                \
        pB3 = *(const float4*)(gBl + (K0) + 8);            \
    }
    G64_LOAD(0);

    for (int k0 = 0; k0 < Kd; k0 += 64) {
        __syncthreads();
        *(float4*)&sAh[sr * 72 + sc]     = pA0;
        *(float4*)&sAh[sr * 72 + sc + 8] = pA1;
        *(float4*)&sAl[sr * 72 + sc]     = pA2;
        *(float4*)&sAl[sr * 72 + sc + 8] = pA3;
        *(float4*)&sBh[sr * 72 + sc]     = pB0;
        *(float4*)&sBh[sr * 72 + sc + 8] = pB1;
        *(float4*)&sBl[sr * 72 + sc]     = pB2;
        *(float4*)&sBl[sr * 72 + sc + 8] = pB3;
        __syncthreads();
        if (k0 + 64 < Kd) G64_LOAD(k0 + 64);

#pragma unroll
        for (int ks = 0; ks < 2; ks++) {
            bf16x8 ah[2], al[2], bh[2], bl[2];
#pragma unroll
            for (int rt = 0; rt < 2; rt++) {
                int r = wr * 32 + rt * 16 + am;
                ah[rt] = *(const bf16x8*)&sAh[r * 72 + ks * 32 + qk];
                al[rt] = *(const bf16x8*)&sAl[r * 72 + ks * 32 + qk];
            }
#pragma unroll
            for (int ct = 0; ct < 2; ct++) {
                int c = wc * 32 + ct * 16 + am;
                bh[ct] = *(const bf16x8*)&sBh[c * 72 + ks * 32 + qk];
                bl[ct] = *(const bf16x8*)&sBl[c * 72 + ks * 32 + qk];
            }
#pragma unroll
            for (int rt = 0; rt < 2; rt++)
#pragma unroll
                for (int ct = 0; ct < 2; ct++) {
                    acc[rt][ct] = __builtin_amdgcn_mfma_f32_16x16x32_bf16(ah[rt], bh[ct], acc[rt][ct], 0, 0, 0);
                    acc[rt][ct] = __builtin_amdgcn_mfma_f32_16x16x32_bf16(ah[rt], bl[ct], acc[rt][ct], 0, 0, 0);
                    acc[rt][ct] = __builtin_amdgcn_mfma_f32_16x16x32_bf16(al[rt], bh[ct], acc[rt][ct], 0, 0, 0);
                }
        }
    }
#undef G64_LOAD

    int rq = (lane >> 4) * 4;
#pragma unroll
    for (int rt = 0; rt < 2; rt++)
#pragma unroll
        for (int ct = 0; ct < 2; ct++) {
            int col = col0 + wc * 32 + ct * 16 + am;
#pragma unroll
            for (int rg = 0; rg < 4; rg++) {
                int row = row0 + wr * 32 + rt * 16 + rq + rg;
                float v = acc[rt][ct][rg];
                if (col < split_col) {
                    if (bias_lo) v += bias_lo[col];
                    size_t idx = (size_t)row * split_col + col;
                    unsigned short hh = f2bf(v);
                    Chi[idx] = hh;
                    Clo[idx] = f2bf(v - bf2f(hh));
                } else {
                    if (bias_hi) v += bias_hi[col - split_col];
                    Cf[(size_t)row * (N - split_col) + col - split_col] = v;
                }
            }
        }
}

// ---------------------------------------------------------------------------
// Fused index scores + top-K membership (R8-exact: R0's 4-rows/block compute
// loop, 64x132 tile, 16 staging barriers; barrier-free radix).
// ---------------------------------------------------------------------------
__global__ __launch_bounds__(256) void score_topk_kernel(
    const float* __restrict__ qIk,
    const int* __restrict__ coords, const float* __restrict__ rpe_table,
    const float* __restrict__ W1g, const float* __restrict__ b1g,
    const float* __restrict__ W2g, const float* __restrict__ b2g,
    unsigned* __restrict__ selmask)
{
    __shared__ float skI[64][132];
    __shared__ float sqI2[4][IDH2_];
    __shared__ unsigned skeys[4][LI_];
    __shared__ int shist[4][256];
    __shared__ float srpe[NBUCK_ * IH_];
    __shared__ float sW1[GH_ * IH_], sb1[GH_], sW2[IH_ * GH_], sb2[IH_];

    int tid  = threadIdx.x;
    int lane = tid & 63;
    int wv   = tid >> 6;
    int row  = blockIdx.x * 4 + wv;
    int n    = (blockIdx.x * 4) >> 9;

    for (int i = tid; i < NBUCK_ * IH_; i += 256) srpe[i] = rpe_table[i];
    if (tid < 32) sW1[tid] = W1g[tid];
    else if (tid < 64) sW2[tid - 32] = W2g[tid - 32];
    else if (tid < 72) sb1[tid - 64] = b1g[tid - 64];
    else if (tid < 76) sb2[tid - 72] = b2g[tid - 72];
    for (int i = tid; i < 4 * IDH2_; i += 256)
        sqI2[i >> 7][i & 127] =
            qIk[(size_t)(blockIdx.x * 4 + (i >> 7)) * 256 + (i & 127)];
    int pq = coords[row * 2 + 1];

    for (int kt = 0; kt < 8; kt++) {
        __syncthreads();
        {
            int r  = tid >> 2;
            int d0 = (tid & 3) * 32;
            const float* src = qIk + (size_t)(n * LI_ + kt * 64 + r) * 256 + 128 + d0;
#pragma unroll
            for (int j = 0; j < 8; j++)
                *(float4*)&skI[r][d0 + j * 4] = *(const float4*)(src + j * 4);
        }
        __syncthreads();

        int kloc = lane;
        int kg   = kt * 64 + kloc;
        const float* sq = &sqI2[wv][0];
        float dh[8];
#pragma unroll
        for (int hh = 0; hh < 8; hh++) {
            float acc = 0.0f;
#pragma unroll
            for (int d = 0; d < 16; d += 4) {
                float4 kv = *(const float4*)&skI[kloc][hh * 16 + d];
                acc += sq[hh * 16 + d + 0] * kv.x + sq[hh * 16 + d + 1] * kv.y +
                       sq[hh * 16 + d + 2] * kv.z + sq[hh * 16 + d + 3] * kv.w;
            }
            dh[hh] = acc;
        }
        int pk = coords[(n * LI_ + kg) * 2 + 1];
        int rel = pq - pk;
        rel = rel < -MAXREL_ ? -MAXREL_ : (rel > MAXREL_ ? MAXREL_ : rel);
        const float* rp = srpe + (rel + MAXREL_) * IH_;
        float t1[GH_];
#pragma unroll
        for (int g = 0; g < GH_; g++) t1[g] = sb1[g];
#pragma unroll
        for (int j = 0; j < IH_; j++) {
            float gate = dh[IH_ + j] + rp[j];
#pragma unroll
            for (int g = 0; g < GH_; g++) t1[g] += gate * sW1[g * IH_ + j];
        }
#pragma unroll
        for (int g = 0; g < GH_; g++) t1[g] = fmaxf(t1[g], 0.0f);
        float score = 0.0f;
#pragma unroll
        for (int j = 0; j < IH_; j++) {
            float t2 = sb2[j];
#pragma unroll
            for (int g = 0; g < GH_; g++) t2 += t1[g] * sW2[j * GH_ + g];
            float sg = 1.0f / (1.0f + expf(-t2));
            float rs = fmaxf(dh[j] + rp[j], 0.0f);
            score += rs * sg;
        }
        unsigned bits = __float_as_uint(score);
        skeys[wv][kg] = (bits & 0x80000000u) ? ~bits : (bits | 0x80000000u);
    }
    // no barrier: skeys[wv]/shist[wv] per-wave; same-wave DS ops in-order

    unsigned pref = 0u;
    int kcur = K_;
    const unsigned himask[4] = {0u, 0xFF000000u, 0xFFFF0000u, 0xFFFFFF00u};
#pragma unroll
    for (int pass = 0; pass < 4; pass++) {
        int shift = 24 - pass * 8;
        unsigned hm = himask[pass];
        *(int4*)&shist[wv][4 * lane] = make_int4(0, 0, 0, 0);
#pragma unroll
        for (int c = 0; c < 8; c++) {
            unsigned key = skeys[wv][c * 64 + lane];
            if ((key & hm) == pref) atomicAdd(&shist[wv][(key >> shift) & 255], 1);
        }
        int4 b4 = *(const int4*)&shist[wv][4 * lane];
        int b[4] = {b4.x, b4.y, b4.z, b4.w};
        int t = b[0] + b[1] + b[2] + b[3];
        int Ssum = t;
#pragma unroll
        for (int off = 1; off < 64; off <<= 1) {
            int u = __shfl_down(Ssum, off, 64);
            if (lane + off < 64) Ssum += u;
        }
        int E = Ssum - t;
        int cs[5];
        cs[4] = E;
        cs[3] = b[3] + E;
        cs[2] = b[2] + cs[3];
        cs[1] = b[1] + cs[2];
        cs[0] = b[0] + cs[1];
        bool found = false;
        unsigned cpref = 0u; int ck = 0;
#pragma unroll
        for (int j = 0; j < 4; j++) {
            if (!found && cs[j] >= kcur && cs[j + 1] < kcur) {
                found = true;
                cpref = pref | ((unsigned)(4 * lane + j) << shift);
                ck = kcur - cs[j + 1];
            }
        }
        unsigned long long bm = __ballot(found);
        int src = __ffsll((long long)bm) - 1;
        pref = (unsigned)__shfl((int)cpref, src, 64);
        kcur = __shfl(ck, src, 64);
    }
    unsigned Tu = pref;

    unsigned long long bg[8], be[8];
#pragma unroll
    for (int c = 0; c < 8; c++) {
        unsigned key = skeys[wv][c * 64 + lane];
        bg[c] = __ballot(key > Tu);
        be[c] = __ballot(key == Tu);
    }
    if (lane < 16) {
        int total_gt = 0;
#pragma unroll
        for (int c = 0; c < 8; c++) total_gt += __popcll(bg[c]);
        int base = 0;
#pragma unroll
        for (int c = 0; c < 8; c++) {
            if (2 * c < lane)     base += __popc((unsigned)be[c]);
            if (2 * c + 1 < lane) base += __popc((unsigned)(be[c] >> 32));
        }
        unsigned gw = (unsigned)(bg[lane >> 1] >> (32 * (lane & 1)));
        unsigned ew = (unsigned)(be[lane >> 1] >> (32 * (lane & 1)));
        int ne = K_ - total_gt - base;
        int pc = __popc(ew);
        int m = ne < 0 ? 0 : (ne > pc ? pc : ne);
        while (pc > m) { ew ^= (1u << (31 - __clz(ew))); pc--; }
        selmask[(size_t)row * 16 + lane] = gw | ew;
    }
}

// ---------------------------------------------------------------------------
// Dense-masked attention v7 (R7-exact): T14 async-STAGE prefetch, Q frags
// hoisted, setprio around MFMA clusters, separate P buffer, 2 barriers/kt.
// ---------------------------------------------------------------------------
__global__ __launch_bounds__(256) void attn_kernel(
    const unsigned short* __restrict__ qkvh, const unsigned short* __restrict__ qkvl,
    const unsigned* __restrict__ selmask,
    unsigned short* __restrict__ outh, unsigned short* __restrict__ outl)
{
    __shared__ unsigned short Qh[64 * 72],  Ql[64 * 72];   // [q][d]
    __shared__ unsigned short Kh[64 * 72],  Kl[64 * 72];   // [key][d]
    __shared__ unsigned short VTh[64 * 72], VTl[64 * 72];  // V^T [d][key]
    __shared__ unsigned short Ph[64 * 72],  Pl[64 * 72];   // P [q][key]
    __shared__ unsigned Ms[64][16];

    int b  = blockIdx.x;
    int qt = b >> 6;                 // XCD swizzle: qt in high bits
    int nh = b & 63;
    int h  = nh & 15;
    int n  = nh >> 4;
    int tid = threadIdx.x;
    int lane = tid & 63, w = tid >> 6;
    int lane15 = lane & 15, quad = lane >> 4;
    int q0 = n * LI_ + qt * 64;

    for (int i = tid; i < 64 * 16; i += 256)
        Ms[i >> 4][i & 15] = selmask[(size_t)(q0 + (i >> 4)) * 16 + (i & 15)];

    // stage Q once (already rope'd, scaled, split)
    {
        int r = tid >> 2, c0 = (tid & 3) * 16;
        size_t off = (size_t)(q0 + r) * 3072 + h * 64 + c0;
        *(uint4*)&Qh[r * 72 + c0]     = *(const uint4*)(qkvh + off);
        *(uint4*)&Qh[r * 72 + c0 + 8] = *(const uint4*)(qkvh + off + 8);
        *(uint4*)&Ql[r * 72 + c0]     = *(const uint4*)(qkvl + off);
        *(uint4*)&Ql[r * 72 + c0 + 8] = *(const uint4*)(qkvl + off + 8);
    }
    __syncthreads();   // Q staged -> hoist fragments to registers once
    bf16x8 qfh[2], qfl[2];
#pragma unroll
    for (int ks = 0; ks < 2; ks++) {
        qfh[ks] = *(const bf16x8*)&Qh[(16 * w + lane15) * 72 + ks * 32 + quad * 8];
        qfl[ks] = *(const bf16x8*)&Ql[(16 * w + lane15) * 72 + ks * 32 + quad * 8];
    }

    // prefetch addressing (constant per thread)
    int kr = tid >> 2, kc0 = (tid & 3) * 16;          // K stage coords
    int vd = lane, vk0 = w * 16;                      // V stage coords
    const size_t kbase = (size_t)n * LI_ * 3072 + 1024 + h * 64;
    const size_t vbase = (size_t)n * LI_ * 3072 + 2048 + h * 64;

    uint4 pkh0, pkh1, pkl0, pkl1;                     // K prefetch regs
    unsigned short pvh[16], pvl[16];                  // V prefetch regs

#define LOADT(KT)                                                              \
    {                                                                          \
        size_t offK = kbase + (size_t)((KT) * 64 + kr) * 3072 + kc0;           \
        pkh0 = *(const uint4*)(qkvh + offK);                                   \
        pkh1 = *(const uint4*)(qkvh + offK + 8);                               \
        pkl0 = *(const uint4*)(qkvl + offK);                                   \
        pkl1 = *(const uint4*)(qkvl + offK + 8);                               \
        size_t offV = vbase + (size_t)((KT) * 64 + vk0) * 3072 + vd;           \
        _Pragma("unroll")                                                      \
        for (int j = 0; j < 16; j++) {                                         \
            pvh[j] = qkvh[offV + (size_t)j * 3072];                            \
            pvl[j] = qkvl[offV + (size_t)j * 3072];                            \
        }                                                                      \
    }

    LOADT(0);

    f32x4 o_acc[4];
#pragma unroll
    for (int i = 0; i < 4; i++) o_acc[i] = (f32x4){0.f, 0.f, 0.f, 0.f};
    float rsum[4] = {};

    for (int kt = 0; kt < 8; kt++) {
        __syncthreads();   // prev iter's Kh (QK) and VTh (PV) reads done
        // reg -> LDS writes only (loads were issued last iteration)
        *(uint4*)&Kh[kr * 72 + kc0]      = pkh0;
        *(uint4*)&Kh[kr * 72 + kc0 + 8]  = pkh1;
        *(uint4*)&Kl[kr * 72 + kc0]      = pkl0;
        *(uint4*)&Kl[kr * 72 + kc0 + 8]  = pkl1;
        *(uint4*)&VTh[vd * 72 + vk0]     = *(uint4*)&pvh[0];
        *(uint4*)&VTh[vd * 72 + vk0 + 8] = *(uint4*)&pvh[8];
        *(uint4*)&VTl[vd * 72 + vk0]     = *(uint4*)&pvl[0];
        *(uint4*)&VTl[vd * 72 + vk0 + 8] = *(uint4*)&pvl[8];
        __syncthreads();   // stage visible to all waves

        // issue next tile's loads; latency hides under QK/softmax/PV
        if (kt < 7) LOADT(kt + 1);

        // QK: wave w computes q-tile w vs all 4 key-tiles, bf16x3
        f32x4 s_acc[4];
#pragma unroll
        for (int nt = 0; nt < 4; nt++) s_acc[nt] = (f32x4){0.f, 0.f, 0.f, 0.f};
        __builtin_amdgcn_s_setprio(1);
#pragma unroll
        for (int nt = 0; nt < 4; nt++) {
#pragma unroll
            for (int ks = 0; ks < 2; ks++) {
                bf16x8 kfh = *(const bf16x8*)&Kh[(16 * nt + lane15) * 72 + ks * 32 + quad * 8];
                bf16x8 kfl = *(const bf16x8*)&Kl[(16 * nt + lane15) * 72 + ks * 32 + quad * 8];
                s_acc[nt] = __builtin_amdgcn_mfma_f32_16x16x32_bf16(qfh[ks], kfh, s_acc[nt], 0, 0, 0);
                s_acc[nt] = __builtin_amdgcn_mfma_f32_16x16x32_bf16(qfh[ks], kfl, s_acc[nt], 0, 0, 0);
                s_acc[nt] = __builtin_amdgcn_mfma_f32_16x16x32_bf16(qfl[ks], kfh, s_acc[nt], 0, 0, 0);
            }
        }
        __builtin_amdgcn_s_setprio(0);

        // softmax + P split; writes only this wave's P rows -> no barrier
#pragma unroll
        for (int nt = 0; nt < 4; nt++) {
            int kb = kt * 64 + nt * 16 + lane15;
            int wi = kb >> 5, bit = kb & 31;
#pragma unroll
            for (int reg = 0; reg < 4; reg++) {
                int qloc = 16 * w + quad * 4 + reg;
                unsigned mw = Ms[qloc][wi];
                float p = ((mw >> bit) & 1u) ? __expf(s_acc[nt][reg]) : 0.0f;
                rsum[reg] += p;
                unsigned short ph = f2bf(p);
                Ph[qloc * 72 + nt * 16 + lane15] = ph;
                Pl[qloc * 72 + nt * 16 + lane15] = f2bf(p - bf2f(ph));
            }
        }

        // PV: A = P [q][key] (own rows), B = V^T [d][key], bf16x3
        {
            bf16x8 pfh[2], pfl[2];
#pragma unroll
            for (int ks = 0; ks < 2; ks++) {
                pfh[ks] = *(const bf16x8*)&Ph[(16 * w + lane15) * 72 + ks * 32 + quad * 8];
                pfl[ks] = *(const bf16x8*)&Pl[(16 * w + lane15) * 72 + ks * 32 + quad * 8];
            }
            __builtin_amdgcn_s_setprio(1);
#pragma unroll
            for (int dt = 0; dt < 4; dt++) {
#pragma unroll
                for (int ks = 0; ks < 2; ks++) {
                    bf16x8 vfh = *(const bf16x8*)&VTh[(16 * dt + lane15) * 72 + ks * 32 + quad * 8];
                    bf16x8 vfl = *(const bf16x8*)&VTl[(16 * dt + lane15) * 72 + ks * 32 + quad * 8];
                    o_acc[dt] = __builtin_amdgcn_mfma_f32_16x16x32_bf16(pfh[ks], vfh, o_acc[dt], 0, 0, 0);
                    o_acc[dt] = __builtin_amdgcn_mfma_f32_16x16x32_bf16(pfh[ks], vfl, o_acc[dt], 0, 0, 0);
                    o_acc[dt] = __builtin_amdgcn_mfma_f32_16x16x32_bf16(pfl[ks], vfh, o_acc[dt], 0, 0, 0);
                }
            }
            __builtin_amdgcn_s_setprio(0);
        }
    }
#undef LOADT

    // row sums: reduce over the 16 lanes (lane15) sharing each q row
#pragma unroll
    for (int reg = 0; reg < 4; reg++) {
        rsum[reg] += __shfl_xor(rsum[reg], 1, 64);
        rsum[reg] += __shfl_xor(rsum[reg], 2, 64);
        rsum[reg] += __shfl_xor(rsum[reg], 4, 64);
        rsum[reg] += __shfl_xor(rsum[reg], 8, 64);
    }

    // epilogue: normalize, split hi/lo, store
#pragma unroll
    for (int dt = 0; dt < 4; dt++) {
#pragma unroll
        for (int reg = 0; reg < 4; reg++) {
            float v = o_acc[dt][reg] / rsum[reg];
            size_t ob = (size_t)(q0 + 16 * w + quad * 4 + reg) * 1024 + h * 64 + 16 * dt + lane15;
            unsigned short hh = f2bf(v);
            outh[ob] = hh;
            outl[ob] = f2bf(v - bf2f(hh));
        }
    }
}

// ---------------------------------------------------------------------------
extern "C" void kernel_launch(void* const* d_in, const int* in_sizes, int n_in,
                              void* d_out, int out_size, void* d_ws, size_t ws_size,
                              hipStream_t stream)
{
    const float* hidden  = (const float*)d_in[0];
    const int*   coords  = (const int*)d_in[1];
    const float* rope    = (const float*)d_in[3];
    const float* Wq_idx  = (const float*)d_in[4];
    const float* Wk_idx  = (const float*)d_in[5];
    const float* W1g     = (const float*)d_in[6];
    const float* b1g     = (const float*)d_in[7];
    const float* W2g     = (const float*)d_in[8];
    const float* b2g     = (const float*)d_in[9];
    const float* rpe     = (const float*)d_in[10];
    const float* Wqkv_d  = (const float*)d_in[11];
    const float* bqkv_d  = (const float*)d_in[12];
    const float* Wqkv_u  = (const float*)d_in[13];
    const float* bqkv_u  = (const float*)d_in[14];
    const float* Wp_d    = (const float*)d_in[15];
    const float* bp_d    = (const float*)d_in[16];
    const float* Wp_u    = (const float*)d_in[17];
    const float* bp_u    = (const float*)d_in[18];
    const float* scaler  = (const float*)d_in[19];
    float* out = (float*)d_out;

    unsigned short* sp_hi  = (unsigned short*)d_ws;
    unsigned short* sp_lo  = sp_hi + NSPLIT_;
    unsigned short* mid_hi = sp_lo + NSPLIT_;
    unsigned short* mid_lo = mid_hi + (size_t)S_ * BOT_;
    float* qkv = (float*)(mid_lo + (size_t)S_ * BOT_);   // slot kept (unused)
    float* qIk = qkv + (size_t)S_ * 3 * DIM_;
    unsigned* selmask = (unsigned*)(qIk + (size_t)S_ * 256);
    unsigned short* qkvh = (unsigned short*)(selmask + (size_t)S_ * 16);
    unsigned short* qkvl = qkvh + (size_t)S_ * 3 * DIM_;
    float* cost = (float*)(qkvl + (size_t)S_ * 3 * DIM_);
    float* sint = cost + NTRIG_;

    // 0) split hidden + all weights into hi/lo bf16, precompute cos/sin
    split_all_kernel<<<((NSPLIT_ + NTRIG_) / 4 + 255) / 256, 256, 0, stream>>>(
        hidden, Wqkv_d, Wq_idx, Wk_idx, Wqkv_u, Wp_d, Wp_u, rope,
        sp_hi, sp_lo, cost, sint);

    // 1) fused gemm1: hidden @ [Wqkv_d;Wq;Wk]^T -> mid(hi/lo) + qIk(fp32)
    gemm64_bf16x3<<<dim3(512 / 64, S_ / 64), 256, 0, stream>>>(
        sp_hi, sp_lo, sp_hi + OFF_W1_, sp_lo + OFF_W1_,
        bqkv_d, nullptr, qIk, mid_hi, mid_lo, S_, 512, DIM_, 256);

    // 2) fused index scores + top-k membership (R8-exact, 4 rows/block)
    score_topk_kernel<<<S_ / 4, 256, 0, stream>>>(
        qIk, coords, rpe, W1g, b1g, W2g, b2g, selmask);

    // 3) qkv = mid @ Wqkv_u^T + b, fused RoPE (table cos/sin) + hi/lo split
    gemm_qkv_rope<<<dim3(3 * DIM_ / 64, S_ / 128), 256, 0, stream>>>(
        mid_hi, mid_lo, sp_hi + OFF_WQKVU_, sp_lo + OFF_WQKVU_,
        bqkv_u, cost, sint, qkvh, qkvl);

    // 4) MFMA attention (T14 prefetch; emits attout hi/lo into split slots)
    attn_kernel<<<NIMG_ * H_ * 8, 256, 0, stream>>>(qkvh, qkvl, selmask, sp_hi, sp_lo);

    // 5) mid2 = attout @ Wp_d^T + b (hi/lo)
    gemm64_bf16x3<<<dim3(BOT_ / 64, S_ / 64), 256, 0, stream>>>(
        sp_hi, sp_lo, sp_hi + OFF_WPD_, sp_lo + OFF_WPD_,
        bp_d, nullptr, nullptr, mid_hi, mid_lo, S_, BOT_, DIM_, BOT_);

    // 6) out = mid2 @ Wp_u^T + b, *scaler (fp32)
    gemm_bf16x3<<<dim3(DIM_ / 64, S_ / 128), 256, 0, stream>>>(
        mid_hi, mid_lo, sp_hi + OFF_WPU_, sp_lo + OFF_WPU_,
        bp_u, scaler, out, S_, DIM_, BOT_);
}